// Round 3
// baseline (988.098 us; speedup 1.0000x reference)
//
#include <hip/hip_runtime.h>
#include <cstddef>

#define S_ 32
#define NM1 127
#define D_ 256
#define F_ 516
#define TRI_ 8128
#define G_ 768
#define M_ (S_ * NM1)   // 4064

typedef __bf16 v8bf __attribute__((ext_vector_type(8)));
typedef __bf16 bf2 __attribute__((ext_vector_type(2)));
typedef float v4f __attribute__((ext_vector_type(4)));

#if __has_builtin(__builtin_amdgcn_fdot2_f32_bf16)
#define HAS_DOT2 1
#else
#define HAS_DOT2 0
#endif

__device__ __forceinline__ unsigned short f2bf(float f) {
    unsigned int u = __float_as_uint(f);
    unsigned int r = (u + 0x7FFFu + ((u >> 16) & 1u)) >> 16;
    return (unsigned short)r;
}

__device__ __forceinline__ void store4bf(unsigned short* p, float4 v) {
    ushort4 q;
    q.x = f2bf(v.x); q.y = f2bf(v.y); q.z = f2bf(v.z); q.w = f2bf(v.w);
    *(ushort4*)p = q;
}

__device__ __forceinline__ bf2 u2bf2(unsigned int u) {
    union { unsigned int u; bf2 v; } x; x.u = u; return x.v;
}

__device__ __forceinline__ float bflo(unsigned int u) { return __uint_as_float(u << 16); }
__device__ __forceinline__ float bfhi(unsigned int u) { return __uint_as_float(u & 0xffff0000u); }

__device__ __forceinline__ float sigmoidf_(float x) { return 1.f / (1.f + __expf(-x)); }

// branch-free tanh: copysign(1 - 2/(e^{2|x|}+1), x); e^inf -> inf -> 2/inf=0 -> 1
__device__ __forceinline__ float fast_tanh(float x) {
    float ax = fabsf(x);
    float e = __expf(2.f * ax);
    float t = 1.f - 2.f / (e + 1.f);
    return copysignf(t, x);
}

// ---------------------------------------------------------------------------
// K1: c0 = MLPReadout([z;init]) through cc_*; also zero d_out. 1 block x 1024.
// ---------------------------------------------------------------------------
__global__ __launch_bounds__(1024) void c0_kernel(
    const float* __restrict__ z_ph, const float* __restrict__ init_ph,
    const float* __restrict__ W0, const float* __restrict__ b0,
    const float* __restrict__ W1, const float* __restrict__ b1,
    const float* __restrict__ W2, const float* __restrict__ b2,
    float* __restrict__ c0_out, float* __restrict__ out_zero)
{
    __shared__ float v[512];
    __shared__ float h0[256];
    __shared__ float h1[128];
    __shared__ float red[4][256];
    __shared__ float red1[8][128];
    const int t = threadIdx.x;
    if (t < 512) v[t] = (t < 256) ? z_ph[t] : init_ph[t - 256];
    if (t < 64) out_zero[t] = 0.f;
    __syncthreads();
    {
        int row = t & 255, part = t >> 8;
        const float* w = W0 + (size_t)row * 512 + part * 128;
        const float* vv = v + part * 128;
        float a = 0.f;
        for (int k = 0; k < 128; ++k) a += w[k] * vv[k];
        red[part][row] = a;
    }
    __syncthreads();
    if (t < 256) {
        float a = b0[t] + red[0][t] + red[1][t] + red[2][t] + red[3][t];
        h0[t] = fmaxf(a, 0.f);
    }
    __syncthreads();
    {
        int row = t & 127, part = t >> 7;
        const float* w = W1 + (size_t)row * 256 + part * 32;
        const float* vv = h0 + part * 32;
        float a = 0.f;
        for (int k = 0; k < 32; ++k) a += w[k] * vv[k];
        red1[part][row] = a;
    }
    __syncthreads();
    if (t < 128) {
        float a = b1[t];
        for (int p = 0; p < 8; ++p) a += red1[p][t];
        h1[t] = fmaxf(a, 0.f);
    }
    __syncthreads();
    {
        int row = t & 255, part = t >> 8;
        const float* w = W2 + (size_t)row * 128 + part * 32;
        const float* vv = h1 + part * 32;
        float a = 0.f;
        for (int k = 0; k < 32; ++k) a += w[k] * vv[k];
        red[part][row] = a;
    }
    __syncthreads();
    if (t < 256) c0_out[t] = b2[t] + red[0][t] + red[1][t] + red[2][t] + red[3][t];
}

// ---------------------------------------------------------------------------
// K2: weight fp32 -> bf16 with optional column slice + zero pad.
// dst[n*ldd + k] = (k < K) ? bf16(src[n*lds + off + k]) : 0
// ---------------------------------------------------------------------------
__global__ __launch_bounds__(256) void cvt_w(const float* __restrict__ src,
                                             unsigned short* __restrict__ dst,
                                             int N, int K, int lds_, int off, int ldd)
{
    int idx = blockIdx.x * 256 + threadIdx.x;
    if (idx >= N * ldd) return;
    int n = idx / ldd, k = idx - n * ldd;
    float v = (k < K) ? src[(size_t)n * lds_ + off + k] : 0.f;
    dst[idx] = f2bf(v);
}

// ---------------------------------------------------------------------------
// K2b: pack Whh (768x256 f32) -> wpT (128x768 u32), wpT[p][j] =
//      pack(bf16(Whh[j][2p]) , bf16(Whh[j][2p+1]))
// ---------------------------------------------------------------------------
__global__ __launch_bounds__(256) void pack_whh(const float* __restrict__ W,
                                                unsigned int* __restrict__ wpT)
{
    int idx = blockIdx.x * 256 + threadIdx.x;
    if (idx >= 128 * 768) return;
    int p = idx / 768, j = idx - p * 768;
    float a = W[(size_t)j * 256 + 2 * p];
    float b = W[(size_t)j * 256 + 2 * p + 1];
    wpT[idx] = (unsigned int)f2bf(a) | ((unsigned int)f2bf(b) << 16);
}

// ---------------------------------------------------------------------------
// K3: bf16 MFMA GEMM, 64x64 tile, K chunked by 128, XOR-swizzled LDS.
// C[m,n] = act( dot(Arow(m), B[n, :K]) + bias[n] )
// mode 0: Arow = A + m*lda ; mode 1: x-row gather ; mode 2: content_seq gather
// split: N=512, cols<256 -> C (no bias), cols>=256 -> C2 (+bias[col-256])
// ---------------------------------------------------------------------------
__global__ __launch_bounds__(256) void gemm_mfma(
    const float* __restrict__ A, const unsigned short* __restrict__ B,
    const float* __restrict__ bias, const float* __restrict__ c0,
    float* __restrict__ C, float* __restrict__ C2,
    int M, int N, int K, int lda, int ldb, int mode, int act, int split)
{
    __shared__ __align__(16) unsigned short As[64 * 128];
    __shared__ __align__(16) unsigned short Bs[64 * 128];
    const int tid = threadIdx.x;
    const int m0 = blockIdx.x * 64, n0 = blockIdx.y * 64;
    const int wave = tid >> 6, lane = tid & 63;
    const int lr = lane & 15, quad = lane >> 4;

    v4f acc[4];
    const v4f z4 = {0.f, 0.f, 0.f, 0.f};
#pragma unroll
    for (int nt = 0; nt < 4; ++nt) acc[nt] = z4;

    for (int k0 = 0; k0 < K; k0 += 128) {
        // stage A: 64 rows x 128 k (fp32 -> bf16)
        for (int idx = tid; idx < 64 * 32; idx += 256) {
            int r = idx >> 5, kq = idx & 31;
            int k = k0 + kq * 4;
            int m = m0 + r; if (m > M - 1) m = M - 1;
            float4 a = {0.f, 0.f, 0.f, 0.f};
            if (k < K) {
                const float* Ar;
                if (mode == 1) {
                    int ss = m / 127, tt = m - ss * 127;
                    Ar = A + (size_t)(ss * 128 + tt + 1) * lda;
                } else if (mode == 2) {
                    int tt = m % 127;
                    Ar = (tt == 0) ? c0 : (A + (size_t)(m - 1) * lda);
                } else {
                    Ar = A + (size_t)m * lda;
                }
                a = *(const float4*)&Ar[k];
            }
            store4bf(&As[r * 128 + (((kq >> 1) ^ (r & 7)) << 3) + ((kq & 1) << 2)], a);
        }
        // stage B: 64 cols x 128 k (bf16 direct)
        for (int idx = tid; idx < 64 * 16; idx += 256) {
            int c = idx >> 4, kb = idx & 15;
            int k = k0 + kb * 8;
            int n = n0 + c;
            uint4 bv = {0u, 0u, 0u, 0u};
            if (k < K) bv = *(const uint4*)&B[(size_t)n * ldb + k];
            *(uint4*)&Bs[c * 128 + ((kb ^ (c & 7)) << 3)] = bv;
        }
        __syncthreads();
        const int row = wave * 16 + lr;
        const int rem = K - k0;
        const int kkm = (rem >= 128) ? 4 : ((rem + 31) >> 5);
        for (int kk = 0; kk < kkm; ++kk) {
            const v8bf af = *(const v8bf*)&As[row * 128 + ((((kk << 2) + quad) ^ (row & 7)) << 3)];
#pragma unroll
            for (int nt = 0; nt < 4; ++nt) {
                const int col = nt * 16 + lr;
                const v8bf bf = *(const v8bf*)&Bs[col * 128 + ((((kk << 2) + quad) ^ (col & 7)) << 3)];
                acc[nt] = __builtin_amdgcn_mfma_f32_16x16x32_bf16(af, bf, acc[nt], 0, 0, 0);
            }
        }
        __syncthreads();
    }
#pragma unroll
    for (int nt = 0; nt < 4; ++nt) {
        const int col = n0 + nt * 16 + lr;
#pragma unroll
        for (int r = 0; r < 4; ++r) {
            const int row = m0 + wave * 16 + quad * 4 + r;
            if (row < M) {
                float v = acc[nt][r];
                if (split) {
                    if (col < 256) C[(size_t)row * 256 + col] = v;
                    else C2[(size_t)row * 256 + (col - 256)] = v + bias[col - 256];
                } else {
                    if (bias) v += bias[col];
                    if (act) v = fmaxf(v, 0.f);
                    C[(size_t)row * N + col] = v;
                }
            }
        }
    }
}

// ---------------------------------------------------------------------------
// K4: GRU scan v3. 256 threads/sample; thread j holds Whh rows j, 256+j,
// 512+j register-resident (bf16-pair packed, 384 VGPRs). All 3 dots + gates
// in-register; packed-h double buffer in LDS; ONE barrier per step.
// ---------------------------------------------------------------------------
__global__ __launch_bounds__(256, 1) void gru_scan3(
    const float* __restrict__ gi, const unsigned int* __restrict__ wpT,
    const float* __restrict__ bhh, float* __restrict__ outp, int T)
{
    const int s = blockIdx.x, j = threadIdx.x;
    __shared__ unsigned int hb[2][128];

    unsigned int wr[128], wz[128], wn[128];
#pragma unroll
    for (int p = 0; p < 128; ++p) wr[p] = wpT[p * 768 + j];
#pragma unroll
    for (int p = 0; p < 128; ++p) wz[p] = wpT[p * 768 + 256 + j];
#pragma unroll
    for (int p = 0; p < 128; ++p) wn[p] = wpT[p * 768 + 512 + j];

    const float br = bhh[j], bz = bhh[256 + j], bn = bhh[512 + j];
    const float* g0 = gi + (size_t)s * T * G_;
    float* o0 = outp + (size_t)s * T * D_ + j;
    float g_r = g0[j], g_z = g0[256 + j], g_n = g0[512 + j];
    float h = 0.f;
    if (j < 128) { hb[0][j] = 0u; hb[1][j] = 0u; }
    __syncthreads();

    for (int t = 0; t < T; ++t) {
        // prefetch next step's gi
        float ngr = 0.f, ngz = 0.f, ngn = 0.f;
        if (t + 1 < T) {
            const float* gn_ = g0 + (size_t)(t + 1) * G_;
            ngr = gn_[j]; ngz = gn_[256 + j]; ngn = gn_[512 + j];
        }
        const uint4* hq4 = (const uint4*)hb[t & 1];
        float r0 = 0.f, r1 = 0.f, r2 = 0.f, r3 = 0.f;
        float z0 = 0.f, z1 = 0.f, z2 = 0.f, z3 = 0.f;
        float n0 = 0.f, n1 = 0.f, n2 = 0.f, n3 = 0.f;
#if HAS_DOT2
#pragma unroll
        for (int p4 = 0; p4 < 32; ++p4) {
            const uint4 hq = hq4[p4];
            r0 = __builtin_amdgcn_fdot2_f32_bf16(u2bf2(wr[4 * p4 + 0]), u2bf2(hq.x), r0, false);
            r1 = __builtin_amdgcn_fdot2_f32_bf16(u2bf2(wr[4 * p4 + 1]), u2bf2(hq.y), r1, false);
            r2 = __builtin_amdgcn_fdot2_f32_bf16(u2bf2(wr[4 * p4 + 2]), u2bf2(hq.z), r2, false);
            r3 = __builtin_amdgcn_fdot2_f32_bf16(u2bf2(wr[4 * p4 + 3]), u2bf2(hq.w), r3, false);
            z0 = __builtin_amdgcn_fdot2_f32_bf16(u2bf2(wz[4 * p4 + 0]), u2bf2(hq.x), z0, false);
            z1 = __builtin_amdgcn_fdot2_f32_bf16(u2bf2(wz[4 * p4 + 1]), u2bf2(hq.y), z1, false);
            z2 = __builtin_amdgcn_fdot2_f32_bf16(u2bf2(wz[4 * p4 + 2]), u2bf2(hq.z), z2, false);
            z3 = __builtin_amdgcn_fdot2_f32_bf16(u2bf2(wz[4 * p4 + 3]), u2bf2(hq.w), z3, false);
            n0 = __builtin_amdgcn_fdot2_f32_bf16(u2bf2(wn[4 * p4 + 0]), u2bf2(hq.x), n0, false);
            n1 = __builtin_amdgcn_fdot2_f32_bf16(u2bf2(wn[4 * p4 + 1]), u2bf2(hq.y), n1, false);
            n2 = __builtin_amdgcn_fdot2_f32_bf16(u2bf2(wn[4 * p4 + 2]), u2bf2(hq.z), n2, false);
            n3 = __builtin_amdgcn_fdot2_f32_bf16(u2bf2(wn[4 * p4 + 3]), u2bf2(hq.w), n3, false);
        }
#else
#pragma unroll
        for (int p4 = 0; p4 < 32; ++p4) {
            const uint4 hq = hq4[p4];
            float hx0 = bflo(hq.x), hx1 = bfhi(hq.x), hy0 = bflo(hq.y), hy1 = bfhi(hq.y);
            float hz0 = bflo(hq.z), hz1 = bfhi(hq.z), hw0 = bflo(hq.w), hw1 = bfhi(hq.w);
            r0 += bflo(wr[4*p4+0])*hx0 + bfhi(wr[4*p4+0])*hx1;
            r1 += bflo(wr[4*p4+1])*hy0 + bfhi(wr[4*p4+1])*hy1;
            r2 += bflo(wr[4*p4+2])*hz0 + bfhi(wr[4*p4+2])*hz1;
            r3 += bflo(wr[4*p4+3])*hw0 + bfhi(wr[4*p4+3])*hw1;
            z0 += bflo(wz[4*p4+0])*hx0 + bfhi(wz[4*p4+0])*hx1;
            z1 += bflo(wz[4*p4+1])*hy0 + bfhi(wz[4*p4+1])*hy1;
            z2 += bflo(wz[4*p4+2])*hz0 + bfhi(wz[4*p4+2])*hz1;
            z3 += bflo(wz[4*p4+3])*hw0 + bfhi(wz[4*p4+3])*hw1;
            n0 += bflo(wn[4*p4+0])*hx0 + bfhi(wn[4*p4+0])*hx1;
            n1 += bflo(wn[4*p4+1])*hy0 + bfhi(wn[4*p4+1])*hy1;
            n2 += bflo(wn[4*p4+2])*hz0 + bfhi(wn[4*p4+2])*hz1;
            n3 += bflo(wn[4*p4+3])*hw0 + bfhi(wn[4*p4+3])*hw1;
        }
#endif
        const float dr = (r0 + r1) + (r2 + r3);
        const float dz = (z0 + z1) + (z2 + z3);
        const float dn = (n0 + n1) + (n2 + n3);
        const float rg = sigmoidf_(g_r + dr + br);
        const float zg = sigmoidf_(g_z + dz + bz);
        const float ng = fast_tanh(g_n + rg * (dn + bn));
        const float hnew = ng + zg * (h - ng);
        h = hnew;
        o0[(size_t)t * D_] = hnew;
        const float hoth = __shfl_xor(hnew, 1);
        if ((j & 1) == 0) {
            hb[(t + 1) & 1][j >> 1] =
                (unsigned int)f2bf(hnew) | ((unsigned int)f2bf(hoth) << 16);
        }
        g_r = ngr; g_z = ngz; g_n = ngn;
        __syncthreads();
    }
}

// ---------------------------------------------------------------------------
// K5: fused edge readout. 64 edges/block. XOR-swizzled h1 tile in LDS.
// ---------------------------------------------------------------------------
__global__ __launch_bounds__(256) void edge_kernel(
    const float* __restrict__ Amat, const float* __restrict__ Bmat,
    const unsigned short* __restrict__ w1bf, const float* __restrict__ b1,
    const float* __restrict__ W2, const float* __restrict__ b2,
    const float* __restrict__ con, float* __restrict__ out)
{
    __shared__ __align__(16) unsigned short h1s[64 * 256];
    __shared__ int ijs[128];
    __shared__ float redw[4][2];
    const int tid = threadIdx.x;
    const int s = blockIdx.y;
    const int e0 = blockIdx.x * 64;

    if (tid < 64) {
        int e = e0 + tid;
        int i = (int)((sqrtf(8.f * (float)e + 1.f) - 1.f) * 0.5f);
        while (((i + 1) * (i + 2)) / 2 <= e) ++i;
        while ((i * (i + 1)) / 2 > e) --i;
        ijs[tid * 2] = i;
        ijs[tid * 2 + 1] = e - (i * (i + 1)) / 2;
    }
    __syncthreads();

    for (int idx = tid; idx < 64 * 64; idx += 256) {
        int e = idx >> 6, k4 = idx & 63;
        int i = ijs[e * 2], j = ijs[e * 2 + 1];
        float4 a = ((const float4*)(Amat + ((size_t)s * NM1 + j) * D_))[k4];
        float4 b = ((const float4*)(Bmat + ((size_t)s * NM1 + i) * D_))[k4];
        float4 hv;
        hv.x = fmaxf(a.x + b.x, 0.f);
        hv.y = fmaxf(a.y + b.y, 0.f);
        hv.z = fmaxf(a.z + b.z, 0.f);
        hv.w = fmaxf(a.w + b.w, 0.f);
        int pc = (k4 >> 1) ^ (e & 7);
        store4bf(&h1s[e * 256 + (pc << 3) + ((k4 & 1) << 2)], hv);
    }
    __syncthreads();

    const int wave = tid >> 6, lane = tid & 63;
    const int lr = lane & 15, quad = lane >> 4;
    const int row = wave * 16 + lr;

    v4f acc[8];
    const v4f vzero = {0.f, 0.f, 0.f, 0.f};
#pragma unroll
    for (int nt = 0; nt < 8; ++nt) acc[nt] = vzero;

#pragma unroll
    for (int kt = 0; kt < 8; ++kt) {
        const int c = kt * 4 + quad;
        const int pc = c ^ (row & 7);
        const v8bf afrag = *reinterpret_cast<const v8bf*>(&h1s[row * 256 + (pc << 3)]);
        const int ko = kt * 32 + quad * 8;
#pragma unroll
        for (int nt = 0; nt < 8; ++nt) {
            const v8bf bfrag = *reinterpret_cast<const v8bf*>(&w1bf[(size_t)(nt * 16 + lr) * D_ + ko]);
            acc[nt] = __builtin_amdgcn_mfma_f32_16x16x32_bf16(afrag, bfrag, acc[nt], 0, 0, 0);
        }
    }

    float w20[8], w21[8], b1v[8];
#pragma unroll
    for (int nt = 0; nt < 8; ++nt) {
        int oc = nt * 16 + lr;
        w20[nt] = W2[oc];
        w21[nt] = W2[128 + oc];
        b1v[nt] = b1[oc];
    }
    const float cb20 = b2[0], cb21 = b2[1];
    float bsum0 = 0.f, bsum1 = 0.f;
#pragma unroll
    for (int r = 0; r < 4; ++r) {
        float l0 = 0.f, l1 = 0.f;
#pragma unroll
        for (int nt = 0; nt < 8; ++nt) {
            float h2 = fmaxf(acc[nt][r] + b1v[nt], 0.f);
            l0 += h2 * w20[nt];
            l1 += h2 * w21[nt];
        }
#pragma unroll
        for (int d = 1; d < 16; d <<= 1) {
            l0 += __shfl_xor(l0, d);
            l1 += __shfl_xor(l1, d);
        }
        if (lr == 0) {
            int e = e0 + wave * 16 + quad * 4 + r;
            l0 += cb20; l1 += cb21;
            float mx = fmaxf(l0, l1);
            float lse = mx + logf(__expf(l0 - mx) + __expf(l1 - mx));
            float lp0 = fmaxf(l0 - lse, -100.f);
            float lp1 = fmaxf(l1 - lse, -100.f);
            float c0v = con[((size_t)s * TRI_ + e) * 2];
            float c1v = con[((size_t)s * TRI_ + e) * 2 + 1];
            bsum0 -= c0v * lp0 + (1.f - c0v) * lp1;
            bsum1 -= c1v * lp1 + (1.f - c1v) * lp0;
        }
    }
#pragma unroll
    for (int d = 1; d < 64; d <<= 1) {
        bsum0 += __shfl_xor(bsum0, d);
        bsum1 += __shfl_xor(bsum1, d);
    }
    if (lane == 0) { redw[wave][0] = bsum0; redw[wave][1] = bsum1; }
    __syncthreads();
    if (tid == 0) {
        float t0 = redw[0][0] + redw[1][0] + redw[2][0] + redw[3][0];
        float t1 = redw[0][1] + redw[1][1] + redw[2][1] + redw[3][1];
        atomicAdd(&out[s * 2], t0);
        atomicAdd(&out[s * 2 + 1], t1);
    }
}

// ---------------------------------------------------------------------------
extern "C" void kernel_launch(void* const* d_in, const int* in_sizes, int n_in,
                              void* d_out, int out_size, void* d_ws, size_t ws_size,
                              hipStream_t stream)
{
    (void)in_sizes; (void)n_in; (void)out_size; (void)ws_size;
    const float* x        = (const float*)d_in[0];
    const float* con      = (const float*)d_in[1];
    const float* z_ph     = (const float*)d_in[2];
    const float* init_ph  = (const float*)d_in[3];
    const float* cc_W0    = (const float*)d_in[4];
    const float* cc_b0    = (const float*)d_in[5];
    const float* cc_W1    = (const float*)d_in[6];
    const float* cc_b1    = (const float*)d_in[7];
    const float* cc_W2    = (const float*)d_in[8];
    const float* cc_b2    = (const float*)d_in[9];
    const float* er_W0    = (const float*)d_in[10];
    const float* er_b0    = (const float*)d_in[11];
    const float* er_W1    = (const float*)d_in[12];
    const float* er_b1    = (const float*)d_in[13];
    const float* er_W2    = (const float*)d_in[14];
    const float* er_b2    = (const float*)d_in[15];
    const float* rr_W     = (const float*)d_in[16];
    const float* rr_b     = (const float*)d_in[17];
    const float* dec_Wih  = (const float*)d_in[18];
    const float* dec_Whh  = (const float*)d_in[19];
    const float* dec_bih  = (const float*)d_in[20];
    const float* dec_bhh  = (const float*)d_in[21];
    const float* upd_Wih  = (const float*)d_in[22];
    const float* upd_Whh  = (const float*)d_in[23];
    const float* upd_bih  = (const float*)d_in[24];
    const float* upd_bhh  = (const float*)d_in[25];
    float* out = (float*)d_out;

    float* ws = (float*)d_ws;
    float* c0v  = ws;                               // 256
    float* gi   = ws + 256;                         // M_*G_
    float* bufA = gi + (size_t)M_ * G_;             // M_*D_ (rnninp, Amat)
    float* bufB = bufA + (size_t)M_ * D_;           // M_*D_ (u_out, Bmat)
    float* memb = bufB + (size_t)M_ * D_;           // M_*D_ (mem)
    unsigned short* w1bf = (unsigned short*)(memb + (size_t)M_ * D_); // 128*256
    unsigned int* wpU = (unsigned int*)(w1bf + 128 * 256);            // 128*768
    unsigned int* wpD = wpU + 128 * 768;                              // 128*768
    unsigned short* rwbf = (unsigned short*)(wpD + 128 * 768);        // 256*520
    unsigned short* uwbf = rwbf + 256 * 520;                          // 768*256
    unsigned short* dwbf = uwbf + 768 * 256;                          // 768*256
    unsigned short* w0bf = dwbf + 768 * 256;                          // 512*256

    // 1) c0 + zero out; weight prep
    c0_kernel<<<1, 1024, 0, stream>>>(z_ph, init_ph, cc_W0, cc_b0, cc_W1, cc_b1,
                                      cc_W2, cc_b2, c0v, out);
    pack_whh<<<(128 * 768 + 255) / 256, 256, 0, stream>>>(upd_Whh, wpU);
    pack_whh<<<(128 * 768 + 255) / 256, 256, 0, stream>>>(dec_Whh, wpD);
    cvt_w<<<(256 * 520 + 255) / 256, 256, 0, stream>>>(rr_W, rwbf, 256, 516, 516, 0, 520);
    cvt_w<<<(768 * 256 + 255) / 256, 256, 0, stream>>>(upd_Wih, uwbf, 768, 256, 256, 0, 256);
    cvt_w<<<(768 * 256 + 255) / 256, 256, 0, stream>>>(dec_Wih, dwbf, 768, 256, 256, 0, 256);
    cvt_w<<<(256 * 256 + 255) / 256, 256, 0, stream>>>(er_W0, w0bf, 256, 256, 512, 0, 256);
    cvt_w<<<(256 * 256 + 255) / 256, 256, 0, stream>>>(er_W0, w0bf + 256 * 256, 256, 256, 512, 256, 256);
    cvt_w<<<(128 * 256 + 255) / 256, 256, 0, stream>>>(er_W1, w1bf, 128, 256, 256, 0, 256);

    // 2) rnninp = relu(x[:,1:] @ rr_W.T + rr_b)   -> bufA
    gemm_mfma<<<dim3((M_ + 63) / 64, 256 / 64), 256, 0, stream>>>(
        x, rwbf, rr_b, nullptr, bufA, nullptr, M_, 256, 516, 516, 520, 1, 1, 0);
    // 3) gi_u = rnninp @ upd_Wih.T + upd_bih      -> gi
    gemm_mfma<<<dim3((M_ + 63) / 64, 768 / 64), 256, 0, stream>>>(
        bufA, uwbf, upd_bih, nullptr, gi, nullptr, M_, 768, 256, 256, 256, 0, 0, 0);
    // 4) u_out = GRU(gi_u; upd)                   -> bufB
    gru_scan3<<<S_, 256, 0, stream>>>(gi, wpU, upd_bhh, bufB, NM1);
    // 5) gi_d = content_seq @ dec_Wih.T + dec_bih -> gi
    gemm_mfma<<<dim3((M_ + 63) / 64, 768 / 64), 256, 0, stream>>>(
        bufB, dwbf, dec_bih, c0v, gi, nullptr, M_, 768, 256, 256, 256, 2, 0, 0);
    // 6) mem = GRU(gi_d; dec)                     -> memb
    gru_scan3<<<S_, 256, 0, stream>>>(gi, wpD, dec_bhh, memb, NM1);
    // 7+8) Amat / Bmat = mem @ er_W0 halves (split N=512)
    gemm_mfma<<<dim3((M_ + 63) / 64, 512 / 64), 256, 0, stream>>>(
        memb, w0bf, er_b0, nullptr, bufA, bufB, M_, 512, 256, 256, 256, 0, 0, 1);
    // 9) fused edge readout -> out (atomicAdd)
    edge_kernel<<<dim3(TRI_ / 64, S_), 256, 0, stream>>>(
        bufA, bufB, w1bf, er_b1, er_W2, er_b2, con, out);
}

// Round 4
// 714.839 us; speedup vs baseline: 1.3823x; 1.3823x over previous
//
#include <hip/hip_runtime.h>
#include <cstddef>

#define S_ 32
#define NM1 127
#define D_ 256
#define F_ 516
#define TRI_ 8128
#define G_ 768
#define M_ (S_ * NM1)   // 4064

typedef __bf16 v8bf __attribute__((ext_vector_type(8)));
typedef __bf16 bf2 __attribute__((ext_vector_type(2)));
typedef float v4f __attribute__((ext_vector_type(4)));

#if __has_builtin(__builtin_amdgcn_fdot2_f32_bf16)
#define HAS_DOT2 1
#else
#define HAS_DOT2 0
#endif

__device__ __forceinline__ unsigned short f2bf(float f) {
    unsigned int u = __float_as_uint(f);
    unsigned int r = (u + 0x7FFFu + ((u >> 16) & 1u)) >> 16;
    return (unsigned short)r;
}

__device__ __forceinline__ void store4bf(unsigned short* p, float4 v) {
    ushort4 q;
    q.x = f2bf(v.x); q.y = f2bf(v.y); q.z = f2bf(v.z); q.w = f2bf(v.w);
    *(ushort4*)p = q;
}

__device__ __forceinline__ bf2 u2bf2(unsigned int u) {
    union { unsigned int u; bf2 v; } x; x.u = u; return x.v;
}

__device__ __forceinline__ float bflo(unsigned int u) { return __uint_as_float(u << 16); }
__device__ __forceinline__ float bfhi(unsigned int u) { return __uint_as_float(u & 0xffff0000u); }

__device__ __forceinline__ float dot2bf(unsigned int w, unsigned int hh, float acc) {
#if HAS_DOT2
    return __builtin_amdgcn_fdot2_f32_bf16(u2bf2(w), u2bf2(hh), acc, false);
#else
    return acc + bflo(w) * bflo(hh) + bfhi(w) * bfhi(hh);
#endif
}

__device__ __forceinline__ float sigmoidf_(float x) { return 1.f / (1.f + __expf(-x)); }

// branch-free tanh: copysign(1 - 2/(e^{2|x|}+1), x)
__device__ __forceinline__ float fast_tanh(float x) {
    float ax = fabsf(x);
    float e = __expf(2.f * ax);
    float t = 1.f - 2.f / (e + 1.f);
    return copysignf(t, x);
}

// ---------------------------------------------------------------------------
// K1: c0 = MLPReadout([z;init]) through cc_*; also zero d_out. 1 block x 1024.
// ---------------------------------------------------------------------------
__global__ __launch_bounds__(1024) void c0_kernel(
    const float* __restrict__ z_ph, const float* __restrict__ init_ph,
    const float* __restrict__ W0, const float* __restrict__ b0,
    const float* __restrict__ W1, const float* __restrict__ b1,
    const float* __restrict__ W2, const float* __restrict__ b2,
    float* __restrict__ c0_out, float* __restrict__ out_zero)
{
    __shared__ float v[512];
    __shared__ float h0[256];
    __shared__ float h1[128];
    __shared__ float red[4][256];
    __shared__ float red1[8][128];
    const int t = threadIdx.x;
    if (t < 512) v[t] = (t < 256) ? z_ph[t] : init_ph[t - 256];
    if (t < 64) out_zero[t] = 0.f;
    __syncthreads();
    {
        int row = t & 255, part = t >> 8;
        const float* w = W0 + (size_t)row * 512 + part * 128;
        const float* vv = v + part * 128;
        float a = 0.f;
        for (int k = 0; k < 128; ++k) a += w[k] * vv[k];
        red[part][row] = a;
    }
    __syncthreads();
    if (t < 256) {
        float a = b0[t] + red[0][t] + red[1][t] + red[2][t] + red[3][t];
        h0[t] = fmaxf(a, 0.f);
    }
    __syncthreads();
    {
        int row = t & 127, part = t >> 7;
        const float* w = W1 + (size_t)row * 256 + part * 32;
        const float* vv = h0 + part * 32;
        float a = 0.f;
        for (int k = 0; k < 32; ++k) a += w[k] * vv[k];
        red1[part][row] = a;
    }
    __syncthreads();
    if (t < 128) {
        float a = b1[t];
        for (int p = 0; p < 8; ++p) a += red1[p][t];
        h1[t] = fmaxf(a, 0.f);
    }
    __syncthreads();
    {
        int row = t & 255, part = t >> 8;
        const float* w = W2 + (size_t)row * 128 + part * 32;
        const float* vv = h1 + part * 32;
        float a = 0.f;
        for (int k = 0; k < 32; ++k) a += w[k] * vv[k];
        red[part][row] = a;
    }
    __syncthreads();
    if (t < 256) c0_out[t] = b2[t] + red[0][t] + red[1][t] + red[2][t] + red[3][t];
}

// ---------------------------------------------------------------------------
// K2: fused weight prep: 2x pack_whh + 6x cvt_w in ONE launch (block ranges).
// pack: wpT[p*768+j] = pack(bf16(W[j][2p]), bf16(W[j][2p+1]))   (p<128,j<768)
// cvt : dst[n*ldd+k] = (k<K) ? bf16(src[n*lds+off+k]) : 0
// ---------------------------------------------------------------------------
__device__ __forceinline__ void do_pack(const float* __restrict__ W,
                                        unsigned int* __restrict__ wpT, int idx)
{
    if (idx >= 128 * 768) return;
    int p = idx / 768, j = idx - p * 768;
    float a = W[(size_t)j * 256 + 2 * p];
    float b = W[(size_t)j * 256 + 2 * p + 1];
    wpT[idx] = (unsigned int)f2bf(a) | ((unsigned int)f2bf(b) << 16);
}

__device__ __forceinline__ void do_cvt(const float* __restrict__ src,
                                       unsigned short* __restrict__ dst,
                                       int idx, int N, int K, int lds_, int off, int ldd)
{
    if (idx >= N * ldd) return;
    int n = idx / ldd, k = idx - n * ldd;
    float v = (k < K) ? src[(size_t)n * lds_ + off + k] : 0.f;
    dst[idx] = f2bf(v);
}

// segments (blocks of 256): pack upd 384 | pack dec 384 | rw 520 | uw 768 |
// dw 768 | w0lo 256 | w0hi 256 | w1 128  => total 3464
#define PREP_BLOCKS 3464

__global__ __launch_bounds__(256) void prep_all(
    const float* __restrict__ upd_Whh, unsigned int* __restrict__ wpU,
    const float* __restrict__ dec_Whh, unsigned int* __restrict__ wpD,
    const float* __restrict__ rr_W, unsigned short* __restrict__ rwbf,
    const float* __restrict__ upd_Wih, unsigned short* __restrict__ uwbf,
    const float* __restrict__ dec_Wih, unsigned short* __restrict__ dwbf,
    const float* __restrict__ er_W0, unsigned short* __restrict__ w0bf,
    const float* __restrict__ er_W1, unsigned short* __restrict__ w1bf)
{
    int bid = blockIdx.x;
    const int tid = threadIdx.x;
    if (bid < 384) { do_pack(upd_Whh, wpU, bid * 256 + tid); return; }
    bid -= 384;
    if (bid < 384) { do_pack(dec_Whh, wpD, bid * 256 + tid); return; }
    bid -= 384;
    if (bid < 520) { do_cvt(rr_W, rwbf, bid * 256 + tid, 256, 516, 516, 0, 520); return; }
    bid -= 520;
    if (bid < 768) { do_cvt(upd_Wih, uwbf, bid * 256 + tid, 768, 256, 256, 0, 256); return; }
    bid -= 768;
    if (bid < 768) { do_cvt(dec_Wih, dwbf, bid * 256 + tid, 768, 256, 256, 0, 256); return; }
    bid -= 768;
    if (bid < 256) { do_cvt(er_W0, w0bf, bid * 256 + tid, 256, 256, 512, 0, 256); return; }
    bid -= 256;
    if (bid < 256) { do_cvt(er_W0, w0bf + 256 * 256, bid * 256 + tid, 256, 256, 512, 256, 256); return; }
    bid -= 256;
    do_cvt(er_W1, w1bf, bid * 256 + tid, 128, 256, 256, 0, 256);
}

// ---------------------------------------------------------------------------
// K3: bf16 MFMA GEMM, 64x64 tile, K chunked by 128, XOR-swizzled LDS.
// ---------------------------------------------------------------------------
__global__ __launch_bounds__(256) void gemm_mfma(
    const float* __restrict__ A, const unsigned short* __restrict__ B,
    const float* __restrict__ bias, const float* __restrict__ c0,
    float* __restrict__ C, float* __restrict__ C2,
    int M, int N, int K, int lda, int ldb, int mode, int act, int split)
{
    __shared__ __align__(16) unsigned short As[64 * 128];
    __shared__ __align__(16) unsigned short Bs[64 * 128];
    const int tid = threadIdx.x;
    const int m0 = blockIdx.x * 64, n0 = blockIdx.y * 64;
    const int wave = tid >> 6, lane = tid & 63;
    const int lr = lane & 15, quad = lane >> 4;

    v4f acc[4];
    const v4f z4 = {0.f, 0.f, 0.f, 0.f};
#pragma unroll
    for (int nt = 0; nt < 4; ++nt) acc[nt] = z4;

    for (int k0 = 0; k0 < K; k0 += 128) {
        for (int idx = tid; idx < 64 * 32; idx += 256) {
            int r = idx >> 5, kq = idx & 31;
            int k = k0 + kq * 4;
            int m = m0 + r; if (m > M - 1) m = M - 1;
            float4 a = {0.f, 0.f, 0.f, 0.f};
            if (k < K) {
                const float* Ar;
                if (mode == 1) {
                    int ss = m / 127, tt = m - ss * 127;
                    Ar = A + (size_t)(ss * 128 + tt + 1) * lda;
                } else if (mode == 2) {
                    int tt = m % 127;
                    Ar = (tt == 0) ? c0 : (A + (size_t)(m - 1) * lda);
                } else {
                    Ar = A + (size_t)m * lda;
                }
                a = *(const float4*)&Ar[k];
            }
            store4bf(&As[r * 128 + (((kq >> 1) ^ (r & 7)) << 3) + ((kq & 1) << 2)], a);
        }
        for (int idx = tid; idx < 64 * 16; idx += 256) {
            int c = idx >> 4, kb = idx & 15;
            int k = k0 + kb * 8;
            int n = n0 + c;
            uint4 bv = {0u, 0u, 0u, 0u};
            if (k < K) bv = *(const uint4*)&B[(size_t)n * ldb + k];
            *(uint4*)&Bs[c * 128 + ((kb ^ (c & 7)) << 3)] = bv;
        }
        __syncthreads();
        const int row = wave * 16 + lr;
        const int rem = K - k0;
        const int kkm = (rem >= 128) ? 4 : ((rem + 31) >> 5);
        for (int kk = 0; kk < kkm; ++kk) {
            const v8bf af = *(const v8bf*)&As[row * 128 + ((((kk << 2) + quad) ^ (row & 7)) << 3)];
#pragma unroll
            for (int nt = 0; nt < 4; ++nt) {
                const int col = nt * 16 + lr;
                const v8bf bf = *(const v8bf*)&Bs[col * 128 + ((((kk << 2) + quad) ^ (col & 7)) << 3)];
                acc[nt] = __builtin_amdgcn_mfma_f32_16x16x32_bf16(af, bf, acc[nt], 0, 0, 0);
            }
        }
        __syncthreads();
    }
#pragma unroll
    for (int nt = 0; nt < 4; ++nt) {
        const int col = n0 + nt * 16 + lr;
#pragma unroll
        for (int r = 0; r < 4; ++r) {
            const int row = m0 + wave * 16 + quad * 4 + r;
            if (row < M) {
                float v = acc[nt][r];
                if (split) {
                    if (col < 256) C[(size_t)row * 256 + col] = v;
                    else C2[(size_t)row * 256 + (col - 256)] = v + bias[col - 256];
                } else {
                    if (bias) v += bias[col];
                    if (act) v = fmaxf(v, 0.f);
                    C[(size_t)row * N + col] = v;
                }
            }
        }
    }
}

// ---------------------------------------------------------------------------
// K4: GRU scan v4. 768 threads/sample = 1 Whh row per thread. Half the row
// (p=0..63) register-resident (64 VGPR), half (p=64..127) streamed from L2
// per step via coalesced dword loads (transposed layout, double-buffered
// 16-word chunks). dred carries full gate preactivations (dot+bhh+gi) so the
// gate phase is pure math. 12 waves -> 3/SIMD TLP. NO spill (cap 170).
// ---------------------------------------------------------------------------
__global__ __launch_bounds__(768, 3) void gru_scan4(
    const float* __restrict__ gi, const unsigned int* __restrict__ wpT,
    const float* __restrict__ bhh, float* __restrict__ outp, int T)
{
    const int s = blockIdx.x, j = threadIdx.x;
    __shared__ unsigned int hb[2][128];
    __shared__ float dred[768];
    __shared__ float gns[256];

    unsigned int wh[64];
#pragma unroll
    for (int p = 0; p < 64; ++p) wh[p] = wpT[p * 768 + j];

    const float bj = bhh[j];
    const float* g0 = gi + (size_t)s * T * G_;
    float* o0 = outp + (size_t)s * T * D_;
    float g_cur = g0[j];
    float h = 0.f;
    if (j < 128) { hb[0][j] = 0u; hb[1][j] = 0u; }
    __syncthreads();

    for (int t = 0; t < T; ++t) {
        float g_next = 0.f;
        if (t + 1 < T) g_next = g0[(size_t)(t + 1) * G_ + j];

        // issue first streamed chunk before held dots (overlap L2 latency)
        unsigned int wsb[2][16];
#pragma unroll
        for (int i = 0; i < 16; ++i) wsb[0][i] = wpT[(64 + i) * 768 + j];

        const uint4* hq4 = (const uint4*)hb[t & 1];
        float a0 = 0.f, a1 = 0.f, a2 = 0.f, a3 = 0.f;
#pragma unroll
        for (int q = 0; q < 16; ++q) {
            uint4 hv = hq4[q];
            a0 = dot2bf(wh[4 * q + 0], hv.x, a0);
            a1 = dot2bf(wh[4 * q + 1], hv.y, a1);
            a2 = dot2bf(wh[4 * q + 2], hv.z, a2);
            a3 = dot2bf(wh[4 * q + 3], hv.w, a3);
        }
#pragma unroll
        for (int c = 0; c < 4; ++c) {
            if (c + 1 < 4) {
#pragma unroll
                for (int i = 0; i < 16; ++i)
                    wsb[(c + 1) & 1][i] = wpT[(64 + (c + 1) * 16 + i) * 768 + j];
            }
            const unsigned int* wc = wsb[c & 1];
#pragma unroll
            for (int qq = 0; qq < 4; ++qq) {
                uint4 hv = hq4[16 + c * 4 + qq];
                a0 = dot2bf(wc[4 * qq + 0], hv.x, a0);
                a1 = dot2bf(wc[4 * qq + 1], hv.y, a1);
                a2 = dot2bf(wc[4 * qq + 2], hv.z, a2);
                a3 = dot2bf(wc[4 * qq + 3], hv.w, a3);
            }
        }
        float a = (a0 + a1) + (a2 + a3) + bj;
        if (j < 512) {
            dred[j] = a + g_cur;
        } else {
            dred[j] = a;
            gns[j - 512] = g_cur;
        }
        __syncthreads();
        if (j < 256) {
            const float rg = sigmoidf_(dred[j]);
            const float zg = sigmoidf_(dred[256 + j]);
            const float ng = fast_tanh(gns[j] + rg * dred[512 + j]);
            const float hnew = ng + zg * (h - ng);
            h = hnew;
            o0[(size_t)t * D_ + j] = hnew;
            const float ho = __shfl_xor(hnew, 1);
            if ((j & 1) == 0)
                hb[(t + 1) & 1][j >> 1] =
                    (unsigned int)f2bf(hnew) | ((unsigned int)f2bf(ho) << 16);
        }
        g_cur = g_next;
        __syncthreads();
    }
}

// ---------------------------------------------------------------------------
// K5: fused edge readout. 64 edges/block. XOR-swizzled h1 tile in LDS.
// ---------------------------------------------------------------------------
__global__ __launch_bounds__(256) void edge_kernel(
    const float* __restrict__ Amat, const float* __restrict__ Bmat,
    const unsigned short* __restrict__ w1bf, const float* __restrict__ b1,
    const float* __restrict__ W2, const float* __restrict__ b2,
    const float* __restrict__ con, float* __restrict__ out)
{
    __shared__ __align__(16) unsigned short h1s[64 * 256];
    __shared__ int ijs[128];
    __shared__ float redw[4][2];
    const int tid = threadIdx.x;
    const int s = blockIdx.y;
    const int e0 = blockIdx.x * 64;

    if (tid < 64) {
        int e = e0 + tid;
        int i = (int)((sqrtf(8.f * (float)e + 1.f) - 1.f) * 0.5f);
        while (((i + 1) * (i + 2)) / 2 <= e) ++i;
        while ((i * (i + 1)) / 2 > e) --i;
        ijs[tid * 2] = i;
        ijs[tid * 2 + 1] = e - (i * (i + 1)) / 2;
    }
    __syncthreads();

    for (int idx = tid; idx < 64 * 64; idx += 256) {
        int e = idx >> 6, k4 = idx & 63;
        int i = ijs[e * 2], j = ijs[e * 2 + 1];
        float4 a = ((const float4*)(Amat + ((size_t)s * NM1 + j) * D_))[k4];
        float4 b = ((const float4*)(Bmat + ((size_t)s * NM1 + i) * D_))[k4];
        float4 hv;
        hv.x = fmaxf(a.x + b.x, 0.f);
        hv.y = fmaxf(a.y + b.y, 0.f);
        hv.z = fmaxf(a.z + b.z, 0.f);
        hv.w = fmaxf(a.w + b.w, 0.f);
        int pc = (k4 >> 1) ^ (e & 7);
        store4bf(&h1s[e * 256 + (pc << 3) + ((k4 & 1) << 2)], hv);
    }
    __syncthreads();

    const int wave = tid >> 6, lane = tid & 63;
    const int lr = lane & 15, quad = lane >> 4;
    const int row = wave * 16 + lr;

    v4f acc[8];
    const v4f vzero = {0.f, 0.f, 0.f, 0.f};
#pragma unroll
    for (int nt = 0; nt < 8; ++nt) acc[nt] = vzero;

#pragma unroll
    for (int kt = 0; kt < 8; ++kt) {
        const int c = kt * 4 + quad;
        const int pc = c ^ (row & 7);
        const v8bf afrag = *reinterpret_cast<const v8bf*>(&h1s[row * 256 + (pc << 3)]);
        const int ko = kt * 32 + quad * 8;
#pragma unroll
        for (int nt = 0; nt < 8; ++nt) {
            const v8bf bfrag = *reinterpret_cast<const v8bf*>(&w1bf[(size_t)(nt * 16 + lr) * D_ + ko]);
            acc[nt] = __builtin_amdgcn_mfma_f32_16x16x32_bf16(afrag, bfrag, acc[nt], 0, 0, 0);
        }
    }

    float w20[8], w21[8], b1v[8];
#pragma unroll
    for (int nt = 0; nt < 8; ++nt) {
        int oc = nt * 16 + lr;
        w20[nt] = W2[oc];
        w21[nt] = W2[128 + oc];
        b1v[nt] = b1[oc];
    }
    const float cb20 = b2[0], cb21 = b2[1];
    float bsum0 = 0.f, bsum1 = 0.f;
#pragma unroll
    for (int r = 0; r < 4; ++r) {
        float l0 = 0.f, l1 = 0.f;
#pragma unroll
        for (int nt = 0; nt < 8; ++nt) {
            float h2 = fmaxf(acc[nt][r] + b1v[nt], 0.f);
            l0 += h2 * w20[nt];
            l1 += h2 * w21[nt];
        }
#pragma unroll
        for (int d = 1; d < 16; d <<= 1) {
            l0 += __shfl_xor(l0, d);
            l1 += __shfl_xor(l1, d);
        }
        if (lr == 0) {
            int e = e0 + wave * 16 + quad * 4 + r;
            l0 += cb20; l1 += cb21;
            float mx = fmaxf(l0, l1);
            float lse = mx + logf(__expf(l0 - mx) + __expf(l1 - mx));
            float lp0 = fmaxf(l0 - lse, -100.f);
            float lp1 = fmaxf(l1 - lse, -100.f);
            float c0v = con[((size_t)s * TRI_ + e) * 2];
            float c1v = con[((size_t)s * TRI_ + e) * 2 + 1];
            bsum0 -= c0v * lp0 + (1.f - c0v) * lp1;
            bsum1 -= c1v * lp1 + (1.f - c1v) * lp0;
        }
    }
#pragma unroll
    for (int d = 1; d < 64; d <<= 1) {
        bsum0 += __shfl_xor(bsum0, d);
        bsum1 += __shfl_xor(bsum1, d);
    }
    if (lane == 0) { redw[wave][0] = bsum0; redw[wave][1] = bsum1; }
    __syncthreads();
    if (tid == 0) {
        float t0 = redw[0][0] + redw[1][0] + redw[2][0] + redw[3][0];
        float t1 = redw[0][1] + redw[1][1] + redw[2][1] + redw[3][1];
        atomicAdd(&out[s * 2], t0);
        atomicAdd(&out[s * 2 + 1], t1);
    }
}

// ---------------------------------------------------------------------------
extern "C" void kernel_launch(void* const* d_in, const int* in_sizes, int n_in,
                              void* d_out, int out_size, void* d_ws, size_t ws_size,
                              hipStream_t stream)
{
    (void)in_sizes; (void)n_in; (void)out_size; (void)ws_size;
    const float* x        = (const float*)d_in[0];
    const float* con      = (const float*)d_in[1];
    const float* z_ph     = (const float*)d_in[2];
    const float* init_ph  = (const float*)d_in[3];
    const float* cc_W0    = (const float*)d_in[4];
    const float* cc_b0    = (const float*)d_in[5];
    const float* cc_W1    = (const float*)d_in[6];
    const float* cc_b1    = (const float*)d_in[7];
    const float* cc_W2    = (const float*)d_in[8];
    const float* cc_b2    = (const float*)d_in[9];
    const float* er_W0    = (const float*)d_in[10];
    const float* er_b0    = (const float*)d_in[11];
    const float* er_W1    = (const float*)d_in[12];
    const float* er_b1    = (const float*)d_in[13];
    const float* er_W2    = (const float*)d_in[14];
    const float* er_b2    = (const float*)d_in[15];
    const float* rr_W     = (const float*)d_in[16];
    const float* rr_b     = (const float*)d_in[17];
    const float* dec_Wih  = (const float*)d_in[18];
    const float* dec_Whh  = (const float*)d_in[19];
    const float* dec_bih  = (const float*)d_in[20];
    const float* dec_bhh  = (const float*)d_in[21];
    const float* upd_Wih  = (const float*)d_in[22];
    const float* upd_Whh  = (const float*)d_in[23];
    const float* upd_bih  = (const float*)d_in[24];
    const float* upd_bhh  = (const float*)d_in[25];
    float* out = (float*)d_out;

    float* ws = (float*)d_ws;
    float* c0v  = ws;                               // 256
    float* gi   = ws + 256;                         // M_*G_
    float* bufA = gi + (size_t)M_ * G_;             // M_*D_ (rnninp, Amat)
    float* bufB = bufA + (size_t)M_ * D_;           // M_*D_ (u_out, Bmat)
    float* memb = bufB + (size_t)M_ * D_;           // M_*D_ (mem)
    unsigned short* w1bf = (unsigned short*)(memb + (size_t)M_ * D_); // 128*256
    unsigned int* wpU = (unsigned int*)(w1bf + 128 * 256);            // 128*768
    unsigned int* wpD = wpU + 128 * 768;                              // 128*768
    unsigned short* rwbf = (unsigned short*)(wpD + 128 * 768);        // 256*520
    unsigned short* uwbf = rwbf + 256 * 520;                          // 768*256
    unsigned short* dwbf = uwbf + 768 * 256;                          // 768*256
    unsigned short* w0bf = dwbf + 768 * 256;                          // 512*256

    // 1) c0 + zero out; fused weight prep
    c0_kernel<<<1, 1024, 0, stream>>>(z_ph, init_ph, cc_W0, cc_b0, cc_W1, cc_b1,
                                      cc_W2, cc_b2, c0v, out);
    prep_all<<<PREP_BLOCKS, 256, 0, stream>>>(upd_Whh, wpU, dec_Whh, wpD,
                                              rr_W, rwbf, upd_Wih, uwbf,
                                              dec_Wih, dwbf, er_W0, w0bf,
                                              er_W1, w1bf);
    // 2) rnninp = relu(x[:,1:] @ rr_W.T + rr_b)   -> bufA
    gemm_mfma<<<dim3((M_ + 63) / 64, 256 / 64), 256, 0, stream>>>(
        x, rwbf, rr_b, nullptr, bufA, nullptr, M_, 256, 516, 516, 520, 1, 1, 0);
    // 3) gi_u = rnninp @ upd_Wih.T + upd_bih      -> gi
    gemm_mfma<<<dim3((M_ + 63) / 64, 768 / 64), 256, 0, stream>>>(
        bufA, uwbf, upd_bih, nullptr, gi, nullptr, M_, 768, 256, 256, 256, 0, 0, 0);
    // 4) u_out = GRU(gi_u; upd)                   -> bufB
    gru_scan4<<<S_, 768, 0, stream>>>(gi, wpU, upd_bhh, bufB, NM1);
    // 5) gi_d = content_seq @ dec_Wih.T + dec_bih -> gi
    gemm_mfma<<<dim3((M_ + 63) / 64, 768 / 64), 256, 0, stream>>>(
        bufB, dwbf, dec_bih, c0v, gi, nullptr, M_, 768, 256, 256, 256, 2, 0, 0);
    // 6) mem = GRU(gi_d; dec)                     -> memb
    gru_scan4<<<S_, 768, 0, stream>>>(gi, wpD, dec_bhh, memb, NM1);
    // 7+8) Amat / Bmat = mem @ er_W0 halves (split N=512)
    gemm_mfma<<<dim3((M_ + 63) / 64, 512 / 64), 256, 0, stream>>>(
        memb, w0bf, er_b0, nullptr, bufA, bufB, M_, 512, 256, 256, 256, 0, 0, 1);
    // 9) fused edge readout -> out (atomicAdd)
    edge_kernel<<<dim3(TRI_ / 64, S_), 256, 0, stream>>>(
        bufA, bufB, w1bf, er_b1, er_W2, er_b2, con, out);
}

// Round 5
// 714.727 us; speedup vs baseline: 1.3825x; 1.0002x over previous
//
#include <hip/hip_runtime.h>
#include <cstddef>

#define S_ 32
#define NM1 127
#define D_ 256
#define F_ 516
#define TRI_ 8128
#define G_ 768
#define M_ (S_ * NM1)   // 4064

typedef __bf16 v8bf __attribute__((ext_vector_type(8)));
typedef __bf16 bf2 __attribute__((ext_vector_type(2)));
typedef float v4f __attribute__((ext_vector_type(4)));

#if __has_builtin(__builtin_amdgcn_fdot2_f32_bf16)
#define HAS_DOT2 1
#else
#define HAS_DOT2 0
#endif

__device__ __forceinline__ unsigned short f2bf(float f) {
    unsigned int u = __float_as_uint(f);
    unsigned int r = (u + 0x7FFFu + ((u >> 16) & 1u)) >> 16;
    return (unsigned short)r;
}

__device__ __forceinline__ void store4bf(unsigned short* p, float4 v) {
    ushort4 q;
    q.x = f2bf(v.x); q.y = f2bf(v.y); q.z = f2bf(v.z); q.w = f2bf(v.w);
    *(ushort4*)p = q;
}

__device__ __forceinline__ bf2 u2bf2(unsigned int u) {
    union { unsigned int u; bf2 v; } x; x.u = u; return x.v;
}

__device__ __forceinline__ float bflo(unsigned int u) { return __uint_as_float(u << 16); }
__device__ __forceinline__ float bfhi(unsigned int u) { return __uint_as_float(u & 0xffff0000u); }

__device__ __forceinline__ float dot2bf(unsigned int w, unsigned int hh, float acc) {
#if HAS_DOT2
    return __builtin_amdgcn_fdot2_f32_bf16(u2bf2(w), u2bf2(hh), acc, false);
#else
    return acc + bflo(w) * bflo(hh) + bfhi(w) * bfhi(hh);
#endif
}

__device__ __forceinline__ float sigmoidf_(float x) { return 1.f / (1.f + __expf(-x)); }

// branch-free tanh: copysign(1 - 2/(e^{2|x|}+1), x)
__device__ __forceinline__ float fast_tanh(float x) {
    float ax = fabsf(x);
    float e = __expf(2.f * ax);
    float t = 1.f - 2.f / (e + 1.f);
    return copysignf(t, x);
}

// ---------------------------------------------------------------------------
// K1: c0 = MLPReadout([z;init]) through cc_*; also zero d_out. 1 block x 1024.
// ---------------------------------------------------------------------------
__global__ __launch_bounds__(1024) void c0_kernel(
    const float* __restrict__ z_ph, const float* __restrict__ init_ph,
    const float* __restrict__ W0, const float* __restrict__ b0,
    const float* __restrict__ W1, const float* __restrict__ b1,
    const float* __restrict__ W2, const float* __restrict__ b2,
    float* __restrict__ c0_out, float* __restrict__ out_zero)
{
    __shared__ float v[512];
    __shared__ float h0[256];
    __shared__ float h1[128];
    __shared__ float red[4][256];
    __shared__ float red1[8][128];
    const int t = threadIdx.x;
    if (t < 512) v[t] = (t < 256) ? z_ph[t] : init_ph[t - 256];
    if (t < 64) out_zero[t] = 0.f;
    __syncthreads();
    {
        int row = t & 255, part = t >> 8;
        const float* w = W0 + (size_t)row * 512 + part * 128;
        const float* vv = v + part * 128;
        float a = 0.f;
        for (int k = 0; k < 128; ++k) a += w[k] * vv[k];
        red[part][row] = a;
    }
    __syncthreads();
    if (t < 256) {
        float a = b0[t] + red[0][t] + red[1][t] + red[2][t] + red[3][t];
        h0[t] = fmaxf(a, 0.f);
    }
    __syncthreads();
    {
        int row = t & 127, part = t >> 7;
        const float* w = W1 + (size_t)row * 256 + part * 32;
        const float* vv = h0 + part * 32;
        float a = 0.f;
        for (int k = 0; k < 32; ++k) a += w[k] * vv[k];
        red1[part][row] = a;
    }
    __syncthreads();
    if (t < 128) {
        float a = b1[t];
        for (int p = 0; p < 8; ++p) a += red1[p][t];
        h1[t] = fmaxf(a, 0.f);
    }
    __syncthreads();
    {
        int row = t & 255, part = t >> 8;
        const float* w = W2 + (size_t)row * 128 + part * 32;
        const float* vv = h1 + part * 32;
        float a = 0.f;
        for (int k = 0; k < 32; ++k) a += w[k] * vv[k];
        red[part][row] = a;
    }
    __syncthreads();
    if (t < 256) c0_out[t] = b2[t] + red[0][t] + red[1][t] + red[2][t] + red[3][t];
}

// ---------------------------------------------------------------------------
// K2: fused weight prep (one launch, block ranges):
// pack : wpT[p*768+j] = pack(bf16(W[j][2p]), bf16(W[j][2p+1]))   p<64 (held)
// pack4: ws4[(q*768+j)] = uint4{word(p=64+4q..64+4q+3, col j)}    (streamed)
// cvt  : dst[n*ldd+k] = (k<K) ? bf16(src[n*lds+off+k]) : 0
// ---------------------------------------------------------------------------
__device__ __forceinline__ void do_pack(const float* __restrict__ W,
                                        unsigned int* __restrict__ wpT, int idx)
{
    if (idx >= 64 * 768) return;
    int p = idx / 768, j = idx - p * 768;
    float a = W[(size_t)j * 256 + 2 * p];
    float b = W[(size_t)j * 256 + 2 * p + 1];
    wpT[idx] = (unsigned int)f2bf(a) | ((unsigned int)f2bf(b) << 16);
}

__device__ __forceinline__ void do_pack4(const float* __restrict__ W,
                                         uint4* __restrict__ ws4, int idx)
{
    if (idx >= 16 * 768) return;
    int q = idx / 768, j = idx - q * 768;
    unsigned int wd[4];
#pragma unroll
    for (int i = 0; i < 4; ++i) {
        int p = 64 + 4 * q + i;
        float a = W[(size_t)j * 256 + 2 * p];
        float b = W[(size_t)j * 256 + 2 * p + 1];
        wd[i] = (unsigned int)f2bf(a) | ((unsigned int)f2bf(b) << 16);
    }
    uint4 v; v.x = wd[0]; v.y = wd[1]; v.z = wd[2]; v.w = wd[3];
    ws4[idx] = v;
}

__device__ __forceinline__ void do_cvt(const float* __restrict__ src,
                                       unsigned short* __restrict__ dst,
                                       int idx, int N, int K, int lds_, int off, int ldd)
{
    if (idx >= N * ldd) return;
    int n = idx / ldd, k = idx - n * ldd;
    float v = (k < K) ? src[(size_t)n * lds_ + off + k] : 0.f;
    dst[idx] = f2bf(v);
}

// segments (blocks of 256): packU 192 | packD 192 | p4U 48 | p4D 48 |
// rw 520 | uw 768 | dw 768 | w0lo 256 | w0hi 256 | w1 128  => 3176
#define PREP_BLOCKS 3176

__global__ __launch_bounds__(256) void prep_all(
    const float* __restrict__ upd_Whh, unsigned int* __restrict__ wpU, uint4* __restrict__ ws4U,
    const float* __restrict__ dec_Whh, unsigned int* __restrict__ wpD, uint4* __restrict__ ws4D,
    const float* __restrict__ rr_W, unsigned short* __restrict__ rwbf,
    const float* __restrict__ upd_Wih, unsigned short* __restrict__ uwbf,
    const float* __restrict__ dec_Wih, unsigned short* __restrict__ dwbf,
    const float* __restrict__ er_W0, unsigned short* __restrict__ w0bf,
    const float* __restrict__ er_W1, unsigned short* __restrict__ w1bf)
{
    int bid = blockIdx.x;
    const int tid = threadIdx.x;
    if (bid < 192) { do_pack(upd_Whh, wpU, bid * 256 + tid); return; }
    bid -= 192;
    if (bid < 192) { do_pack(dec_Whh, wpD, bid * 256 + tid); return; }
    bid -= 192;
    if (bid < 48) { do_pack4(upd_Whh, ws4U, bid * 256 + tid); return; }
    bid -= 48;
    if (bid < 48) { do_pack4(dec_Whh, ws4D, bid * 256 + tid); return; }
    bid -= 48;
    if (bid < 520) { do_cvt(rr_W, rwbf, bid * 256 + tid, 256, 516, 516, 0, 520); return; }
    bid -= 520;
    if (bid < 768) { do_cvt(upd_Wih, uwbf, bid * 256 + tid, 768, 256, 256, 0, 256); return; }
    bid -= 768;
    if (bid < 768) { do_cvt(dec_Wih, dwbf, bid * 256 + tid, 768, 256, 256, 0, 256); return; }
    bid -= 768;
    if (bid < 256) { do_cvt(er_W0, w0bf, bid * 256 + tid, 256, 256, 512, 0, 256); return; }
    bid -= 256;
    if (bid < 256) { do_cvt(er_W0, w0bf + 256 * 256, bid * 256 + tid, 256, 256, 512, 256, 256); return; }
    bid -= 256;
    do_cvt(er_W1, w1bf, bid * 256 + tid, 128, 256, 256, 0, 256);
}

// ---------------------------------------------------------------------------
// K3: bf16 MFMA GEMM, 64x64 tile, K chunked by 128, XOR-swizzled LDS.
// ---------------------------------------------------------------------------
__global__ __launch_bounds__(256) void gemm_mfma(
    const float* __restrict__ A, const unsigned short* __restrict__ B,
    const float* __restrict__ bias, const float* __restrict__ c0,
    float* __restrict__ C, float* __restrict__ C2,
    int M, int N, int K, int lda, int ldb, int mode, int act, int split)
{
    __shared__ __align__(16) unsigned short As[64 * 128];
    __shared__ __align__(16) unsigned short Bs[64 * 128];
    const int tid = threadIdx.x;
    const int m0 = blockIdx.x * 64, n0 = blockIdx.y * 64;
    const int wave = tid >> 6, lane = tid & 63;
    const int lr = lane & 15, quad = lane >> 4;

    v4f acc[4];
    const v4f z4 = {0.f, 0.f, 0.f, 0.f};
#pragma unroll
    for (int nt = 0; nt < 4; ++nt) acc[nt] = z4;

    for (int k0 = 0; k0 < K; k0 += 128) {
        for (int idx = tid; idx < 64 * 32; idx += 256) {
            int r = idx >> 5, kq = idx & 31;
            int k = k0 + kq * 4;
            int m = m0 + r; if (m > M - 1) m = M - 1;
            float4 a = {0.f, 0.f, 0.f, 0.f};
            if (k < K) {
                const float* Ar;
                if (mode == 1) {
                    int ss = m / 127, tt = m - ss * 127;
                    Ar = A + (size_t)(ss * 128 + tt + 1) * lda;
                } else if (mode == 2) {
                    int tt = m % 127;
                    Ar = (tt == 0) ? c0 : (A + (size_t)(m - 1) * lda);
                } else {
                    Ar = A + (size_t)m * lda;
                }
                a = *(const float4*)&Ar[k];
            }
            store4bf(&As[r * 128 + (((kq >> 1) ^ (r & 7)) << 3) + ((kq & 1) << 2)], a);
        }
        for (int idx = tid; idx < 64 * 16; idx += 256) {
            int c = idx >> 4, kb = idx & 15;
            int k = k0 + kb * 8;
            int n = n0 + c;
            uint4 bv = {0u, 0u, 0u, 0u};
            if (k < K) bv = *(const uint4*)&B[(size_t)n * ldb + k];
            *(uint4*)&Bs[c * 128 + ((kb ^ (c & 7)) << 3)] = bv;
        }
        __syncthreads();
        const int row = wave * 16 + lr;
        const int rem = K - k0;
        const int kkm = (rem >= 128) ? 4 : ((rem + 31) >> 5);
        for (int kk = 0; kk < kkm; ++kk) {
            const v8bf af = *(const v8bf*)&As[row * 128 + ((((kk << 2) + quad) ^ (row & 7)) << 3)];
#pragma unroll
            for (int nt = 0; nt < 4; ++nt) {
                const int col = nt * 16 + lr;
                const v8bf bf = *(const v8bf*)&Bs[col * 128 + ((((kk << 2) + quad) ^ (col & 7)) << 3)];
                acc[nt] = __builtin_amdgcn_mfma_f32_16x16x32_bf16(af, bf, acc[nt], 0, 0, 0);
            }
        }
        __syncthreads();
    }
#pragma unroll
    for (int nt = 0; nt < 4; ++nt) {
        const int col = n0 + nt * 16 + lr;
#pragma unroll
        for (int r = 0; r < 4; ++r) {
            const int row = m0 + wave * 16 + quad * 4 + r;
            if (row < M) {
                float v = acc[nt][r];
                if (split) {
                    if (col < 256) C[(size_t)row * 256 + col] = v;
                    else C2[(size_t)row * 256 + (col - 256)] = v + bias[col - 256];
                } else {
                    if (bias) v += bias[col];
                    if (act) v = fmaxf(v, 0.f);
                    C[(size_t)row * N + col] = v;
                }
            }
        }
    }
}

// ---------------------------------------------------------------------------
// K4: GRU scan v5. 768 threads/sample = 1 Whh row per thread.
// p=0..63 register-resident (wh[64]); p=64..127 streamed from L2 as
// lane-contiguous uint4 quads (ws4 layout) -> 16 dwordx4/thread/step
// (vs 64 dword in v4: VMEM-issue was the R4 bottleneck). Double-buffered
// 4-uint4 chunks; each uint4 pairs with one hq4 broadcast quad.
// ---------------------------------------------------------------------------
__global__ __launch_bounds__(768, 3) void gru_scan5(
    const float* __restrict__ gi, const unsigned int* __restrict__ wpT,
    const uint4* __restrict__ ws4,
    const float* __restrict__ bhh, float* __restrict__ outp, int T)
{
    const int s = blockIdx.x, j = threadIdx.x;
    __shared__ unsigned int hb[2][128];
    __shared__ float dred[768];
    __shared__ float gns[256];

    unsigned int wh[64];
#pragma unroll
    for (int p = 0; p < 64; ++p) wh[p] = wpT[p * 768 + j];

    const float bj = bhh[j];
    const float* g0 = gi + (size_t)s * T * G_;
    float* o0 = outp + (size_t)s * T * D_;
    float g_cur = g0[j];
    float h = 0.f;
    if (j < 128) { hb[0][j] = 0u; hb[1][j] = 0u; }
    __syncthreads();

    for (int t = 0; t < T; ++t) {
        float g_next = 0.f;
        if (t + 1 < T) g_next = g0[(size_t)(t + 1) * G_ + j];

        // first streamed chunk (q=16..19 quads) in flight before held dots
        uint4 sb[2][4];
#pragma unroll
        for (int i = 0; i < 4; ++i) sb[0][i] = ws4[i * 768 + j];

        const uint4* hq4 = (const uint4*)hb[t & 1];
        float a0 = 0.f, a1 = 0.f, a2 = 0.f, a3 = 0.f;
#pragma unroll
        for (int q = 0; q < 16; ++q) {
            uint4 hv = hq4[q];
            a0 = dot2bf(wh[4 * q + 0], hv.x, a0);
            a1 = dot2bf(wh[4 * q + 1], hv.y, a1);
            a2 = dot2bf(wh[4 * q + 2], hv.z, a2);
            a3 = dot2bf(wh[4 * q + 3], hv.w, a3);
        }
#pragma unroll
        for (int c = 0; c < 4; ++c) {
            if (c + 1 < 4) {
#pragma unroll
                for (int i = 0; i < 4; ++i)
                    sb[(c + 1) & 1][i] = ws4[((c + 1) * 4 + i) * 768 + j];
            }
#pragma unroll
            for (int i = 0; i < 4; ++i) {
                uint4 wv = sb[c & 1][i];
                uint4 hv = hq4[16 + c * 4 + i];
                a0 = dot2bf(wv.x, hv.x, a0);
                a1 = dot2bf(wv.y, hv.y, a1);
                a2 = dot2bf(wv.z, hv.z, a2);
                a3 = dot2bf(wv.w, hv.w, a3);
            }
        }
        float a = (a0 + a1) + (a2 + a3) + bj;
        if (j < 512) {
            dred[j] = a + g_cur;
        } else {
            dred[j] = a;
            gns[j - 512] = g_cur;
        }
        __syncthreads();
        if (j < 256) {
            const float rg = sigmoidf_(dred[j]);
            const float zg = sigmoidf_(dred[256 + j]);
            const float ng = fast_tanh(gns[j] + rg * dred[512 + j]);
            const float hnew = ng + zg * (h - ng);
            h = hnew;
            o0[(size_t)t * D_ + j] = hnew;
            const float ho = __shfl_xor(hnew, 1);
            if ((j & 1) == 0)
                hb[(t + 1) & 1][j >> 1] =
                    (unsigned int)f2bf(hnew) | ((unsigned int)f2bf(ho) << 16);
        }
        g_cur = g_next;
        __syncthreads();
    }
}

// ---------------------------------------------------------------------------
// K5: fused edge readout. 64 edges/block. XOR-swizzled h1 tile in LDS.
// ---------------------------------------------------------------------------
__global__ __launch_bounds__(256) void edge_kernel(
    const float* __restrict__ Amat, const float* __restrict__ Bmat,
    const unsigned short* __restrict__ w1bf, const float* __restrict__ b1,
    const float* __restrict__ W2, const float* __restrict__ b2,
    const float* __restrict__ con, float* __restrict__ out)
{
    __shared__ __align__(16) unsigned short h1s[64 * 256];
    __shared__ int ijs[128];
    __shared__ float redw[4][2];
    const int tid = threadIdx.x;
    const int s = blockIdx.y;
    const int e0 = blockIdx.x * 64;

    if (tid < 64) {
        int e = e0 + tid;
        int i = (int)((sqrtf(8.f * (float)e + 1.f) - 1.f) * 0.5f);
        while (((i + 1) * (i + 2)) / 2 <= e) ++i;
        while ((i * (i + 1)) / 2 > e) --i;
        ijs[tid * 2] = i;
        ijs[tid * 2 + 1] = e - (i * (i + 1)) / 2;
    }
    __syncthreads();

    for (int idx = tid; idx < 64 * 64; idx += 256) {
        int e = idx >> 6, k4 = idx & 63;
        int i = ijs[e * 2], j = ijs[e * 2 + 1];
        float4 a = ((const float4*)(Amat + ((size_t)s * NM1 + j) * D_))[k4];
        float4 b = ((const float4*)(Bmat + ((size_t)s * NM1 + i) * D_))[k4];
        float4 hv;
        hv.x = fmaxf(a.x + b.x, 0.f);
        hv.y = fmaxf(a.y + b.y, 0.f);
        hv.z = fmaxf(a.z + b.z, 0.f);
        hv.w = fmaxf(a.w + b.w, 0.f);
        int pc = (k4 >> 1) ^ (e & 7);
        store4bf(&h1s[e * 256 + (pc << 3) + ((k4 & 1) << 2)], hv);
    }
    __syncthreads();

    const int wave = tid >> 6, lane = tid & 63;
    const int lr = lane & 15, quad = lane >> 4;
    const int row = wave * 16 + lr;

    v4f acc[8];
    const v4f vzero = {0.f, 0.f, 0.f, 0.f};
#pragma unroll
    for (int nt = 0; nt < 8; ++nt) acc[nt] = vzero;

#pragma unroll
    for (int kt = 0; kt < 8; ++kt) {
        const int c = kt * 4 + quad;
        const int pc = c ^ (row & 7);
        const v8bf afrag = *reinterpret_cast<const v8bf*>(&h1s[row * 256 + (pc << 3)]);
        const int ko = kt * 32 + quad * 8;
#pragma unroll
        for (int nt = 0; nt < 8; ++nt) {
            const v8bf bfrag = *reinterpret_cast<const v8bf*>(&w1bf[(size_t)(nt * 16 + lr) * D_ + ko]);
            acc[nt] = __builtin_amdgcn_mfma_f32_16x16x32_bf16(afrag, bfrag, acc[nt], 0, 0, 0);
        }
    }

    float w20[8], w21[8], b1v[8];
#pragma unroll
    for (int nt = 0; nt < 8; ++nt) {
        int oc = nt * 16 + lr;
        w20[nt] = W2[oc];
        w21[nt] = W2[128 + oc];
        b1v[nt] = b1[oc];
    }
    const float cb20 = b2[0], cb21 = b2[1];
    float bsum0 = 0.f, bsum1 = 0.f;
#pragma unroll
    for (int r = 0; r < 4; ++r) {
        float l0 = 0.f, l1 = 0.f;
#pragma unroll
        for (int nt = 0; nt < 8; ++nt) {
            float h2 = fmaxf(acc[nt][r] + b1v[nt], 0.f);
            l0 += h2 * w20[nt];
            l1 += h2 * w21[nt];
        }
#pragma unroll
        for (int d = 1; d < 16; d <<= 1) {
            l0 += __shfl_xor(l0, d);
            l1 += __shfl_xor(l1, d);
        }
        if (lr == 0) {
            int e = e0 + wave * 16 + quad * 4 + r;
            l0 += cb20; l1 += cb21;
            float mx = fmaxf(l0, l1);
            float lse = mx + logf(__expf(l0 - mx) + __expf(l1 - mx));
            float lp0 = fmaxf(l0 - lse, -100.f);
            float lp1 = fmaxf(l1 - lse, -100.f);
            float c0v = con[((size_t)s * TRI_ + e) * 2];
            float c1v = con[((size_t)s * TRI_ + e) * 2 + 1];
            bsum0 -= c0v * lp0 + (1.f - c0v) * lp1;
            bsum1 -= c1v * lp1 + (1.f - c1v) * lp0;
        }
    }
#pragma unroll
    for (int d = 1; d < 64; d <<= 1) {
        bsum0 += __shfl_xor(bsum0, d);
        bsum1 += __shfl_xor(bsum1, d);
    }
    if (lane == 0) { redw[wave][0] = bsum0; redw[wave][1] = bsum1; }
    __syncthreads();
    if (tid == 0) {
        float t0 = redw[0][0] + redw[1][0] + redw[2][0] + redw[3][0];
        float t1 = redw[0][1] + redw[1][1] + redw[2][1] + redw[3][1];
        atomicAdd(&out[s * 2], t0);
        atomicAdd(&out[s * 2 + 1], t1);
    }
}

// ---------------------------------------------------------------------------
extern "C" void kernel_launch(void* const* d_in, const int* in_sizes, int n_in,
                              void* d_out, int out_size, void* d_ws, size_t ws_size,
                              hipStream_t stream)
{
    (void)in_sizes; (void)n_in; (void)out_size; (void)ws_size;
    const float* x        = (const float*)d_in[0];
    const float* con      = (const float*)d_in[1];
    const float* z_ph     = (const float*)d_in[2];
    const float* init_ph  = (const float*)d_in[3];
    const float* cc_W0    = (const float*)d_in[4];
    const float* cc_b0    = (const float*)d_in[5];
    const float* cc_W1    = (const float*)d_in[6];
    const float* cc_b1    = (const float*)d_in[7];
    const float* cc_W2    = (const float*)d_in[8];
    const float* cc_b2    = (const float*)d_in[9];
    const float* er_W0    = (const float*)d_in[10];
    const float* er_b0    = (const float*)d_in[11];
    const float* er_W1    = (const float*)d_in[12];
    const float* er_b1    = (const float*)d_in[13];
    const float* er_W2    = (const float*)d_in[14];
    const float* er_b2    = (const float*)d_in[15];
    const float* rr_W     = (const float*)d_in[16];
    const float* rr_b     = (const float*)d_in[17];
    const float* dec_Wih  = (const float*)d_in[18];
    const float* dec_Whh  = (const float*)d_in[19];
    const float* dec_bih  = (const float*)d_in[20];
    const float* dec_bhh  = (const float*)d_in[21];
    const float* upd_Wih  = (const float*)d_in[22];
    const float* upd_Whh  = (const float*)d_in[23];
    const float* upd_bih  = (const float*)d_in[24];
    const float* upd_bhh  = (const float*)d_in[25];
    float* out = (float*)d_out;

    float* ws = (float*)d_ws;
    float* c0v  = ws;                               // 256
    float* gi   = ws + 256;                         // M_*G_
    float* bufA = gi + (size_t)M_ * G_;             // M_*D_ (rnninp, Amat)
    float* bufB = bufA + (size_t)M_ * D_;           // M_*D_ (u_out, Bmat)
    float* memb = bufB + (size_t)M_ * D_;           // M_*D_ (mem)
    unsigned short* w1bf = (unsigned short*)(memb + (size_t)M_ * D_); // 128*256
    unsigned int* wpU = (unsigned int*)(w1bf + 128 * 256);            // 64*768
    unsigned int* wpD = wpU + 64 * 768;                               // 64*768
    unsigned short* rwbf = (unsigned short*)(wpD + 64 * 768);         // 256*520
    unsigned short* uwbf = rwbf + 256 * 520;                          // 768*256
    unsigned short* dwbf = uwbf + 768 * 256;                          // 768*256
    unsigned short* w0bf = dwbf + 768 * 256;                          // 512*256
    uint4* ws4U = (uint4*)(w0bf + 512 * 256);                         // 16*768 uint4
    uint4* ws4D = ws4U + 16 * 768;                                    // 16*768 uint4

    // 1) c0 + zero out; fused weight prep
    c0_kernel<<<1, 1024, 0, stream>>>(z_ph, init_ph, cc_W0, cc_b0, cc_W1, cc_b1,
                                      cc_W2, cc_b2, c0v, out);
    prep_all<<<PREP_BLOCKS, 256, 0, stream>>>(upd_Whh, wpU, ws4U, dec_Whh, wpD, ws4D,
                                              rr_W, rwbf, upd_Wih, uwbf,
                                              dec_Wih, dwbf, er_W0, w0bf,
                                              er_W1, w1bf);
    // 2) rnninp = relu(x[:,1:] @ rr_W.T + rr_b)   -> bufA
    gemm_mfma<<<dim3((M_ + 63) / 64, 256 / 64), 256, 0, stream>>>(
        x, rwbf, rr_b, nullptr, bufA, nullptr, M_, 256, 516, 516, 520, 1, 1, 0);
    // 3) gi_u = rnninp @ upd_Wih.T + upd_bih      -> gi
    gemm_mfma<<<dim3((M_ + 63) / 64, 768 / 64), 256, 0, stream>>>(
        bufA, uwbf, upd_bih, nullptr, gi, nullptr, M_, 768, 256, 256, 256, 0, 0, 0);
    // 4) u_out = GRU(gi_u; upd)                   -> bufB
    gru_scan5<<<S_, 768, 0, stream>>>(gi, wpU, ws4U, upd_bhh, bufB, NM1);
    // 5) gi_d = content_seq @ dec_Wih.T + dec_bih -> gi
    gemm_mfma<<<dim3((M_ + 63) / 64, 768 / 64), 256, 0, stream>>>(
        bufB, dwbf, dec_bih, c0v, gi, nullptr, M_, 768, 256, 256, 256, 2, 0, 0);
    // 6) mem = GRU(gi_d; dec)                     -> memb
    gru_scan5<<<S_, 768, 0, stream>>>(gi, wpD, ws4D, dec_bhh, memb, NM1);
    // 7+8) Amat / Bmat = mem @ er_W0 halves (split N=512)
    gemm_mfma<<<dim3((M_ + 63) / 64, 512 / 64), 256, 0, stream>>>(
        memb, w0bf, er_b0, nullptr, bufA, bufB, M_, 512, 256, 256, 256, 0, 0, 1);
    // 9) fused edge readout -> out (atomicAdd)
    edge_kernel<<<dim3(TRI_ / 64, S_), 256, 0, stream>>>(
        bufA, bufB, w1bf, er_b1, er_W2, er_b2, con, out);
}

// Round 6
// 682.902 us; speedup vs baseline: 1.4469x; 1.0466x over previous
//
#include <hip/hip_runtime.h>
#include <cstddef>

#define S_ 32
#define NM1 127
#define D_ 256
#define F_ 516
#define TRI_ 8128
#define G_ 768
#define M_ (S_ * NM1)   // 4064

typedef __bf16 v8bf __attribute__((ext_vector_type(8)));
typedef float v4f __attribute__((ext_vector_type(4)));

__device__ __forceinline__ unsigned short f2bf(float f) {
    unsigned int u = __float_as_uint(f);
    unsigned int r = (u + 0x7FFFu + ((u >> 16) & 1u)) >> 16;
    return (unsigned short)r;
}

__device__ __forceinline__ void store4bf(unsigned short* p, float4 v) {
    ushort4 q;
    q.x = f2bf(v.x); q.y = f2bf(v.y); q.z = f2bf(v.z); q.w = f2bf(v.w);
    *(ushort4*)p = q;
}

__device__ __forceinline__ v8bf u4_to_v8bf(uint4 u) {
    union { uint4 u; v8bf v; } x; x.u = u; return x.v;
}

__device__ __forceinline__ float sigmoidf_(float x) { return 1.f / (1.f + __expf(-x)); }

// branch-free tanh: copysign(1 - 2/(e^{2|x|}+1), x)
__device__ __forceinline__ float fast_tanh(float x) {
    float ax = fabsf(x);
    float e = __expf(2.f * ax);
    float t = 1.f - 2.f / (e + 1.f);
    return copysignf(t, x);
}

// ---------------------------------------------------------------------------
// K1: c0 = MLPReadout([z;init]) through cc_*; also zero d_out. 1 block x 1024.
// ---------------------------------------------------------------------------
__global__ __launch_bounds__(1024) void c0_kernel(
    const float* __restrict__ z_ph, const float* __restrict__ init_ph,
    const float* __restrict__ W0, const float* __restrict__ b0,
    const float* __restrict__ W1, const float* __restrict__ b1,
    const float* __restrict__ W2, const float* __restrict__ b2,
    float* __restrict__ c0_out, float* __restrict__ out_zero)
{
    __shared__ float v[512];
    __shared__ float h0[256];
    __shared__ float h1[128];
    __shared__ float red[4][256];
    __shared__ float red1[8][128];
    const int t = threadIdx.x;
    if (t < 512) v[t] = (t < 256) ? z_ph[t] : init_ph[t - 256];
    if (t < 64) out_zero[t] = 0.f;
    __syncthreads();
    {
        int row = t & 255, part = t >> 8;
        const float* w = W0 + (size_t)row * 512 + part * 128;
        const float* vv = v + part * 128;
        float a = 0.f;
        for (int k = 0; k < 128; ++k) a += w[k] * vv[k];
        red[part][row] = a;
    }
    __syncthreads();
    if (t < 256) {
        float a = b0[t] + red[0][t] + red[1][t] + red[2][t] + red[3][t];
        h0[t] = fmaxf(a, 0.f);
    }
    __syncthreads();
    {
        int row = t & 127, part = t >> 7;
        const float* w = W1 + (size_t)row * 256 + part * 32;
        const float* vv = h0 + part * 32;
        float a = 0.f;
        for (int k = 0; k < 32; ++k) a += w[k] * vv[k];
        red1[part][row] = a;
    }
    __syncthreads();
    if (t < 128) {
        float a = b1[t];
        for (int p = 0; p < 8; ++p) a += red1[p][t];
        h1[t] = fmaxf(a, 0.f);
    }
    __syncthreads();
    {
        int row = t & 255, part = t >> 8;
        const float* w = W2 + (size_t)row * 128 + part * 32;
        const float* vv = h1 + part * 32;
        float a = 0.f;
        for (int k = 0; k < 32; ++k) a += w[k] * vv[k];
        red[part][row] = a;
    }
    __syncthreads();
    if (t < 256) c0_out[t] = b2[t] + red[0][t] + red[1][t] + red[2][t] + red[3][t];
}

// ---------------------------------------------------------------------------
// K2: fused weight prep (one launch, block ranges):
// packfrag: Whh (768x256) -> MFMA B-fragment order:
//   wbuf[(ct*8+kk)*64 + lane] = uint4(8 bf16) = W[ct*16+(lane&15)]
//                                               [kk*32+(lane>>4)*8 .. +7]
// cvt: dst[n*ldd+k] = (k<K) ? bf16(src[n*lds+off+k]) : 0
// ---------------------------------------------------------------------------
__device__ __forceinline__ void do_packfrag(const float* __restrict__ W,
                                            uint4* __restrict__ wbuf, int idx)
{
    if (idx >= 48 * 8 * 64) return;
    int ct = idx >> 9;
    int rem = idx & 511;
    int kk = rem >> 6;
    int lane = rem & 63;
    int lr = lane & 15, quad = lane >> 4;
    const float* src = W + (size_t)(ct * 16 + lr) * 256 + kk * 32 + quad * 8;
    unsigned int wd[4];
#pragma unroll
    for (int i = 0; i < 4; ++i)
        wd[i] = (unsigned int)f2bf(src[2 * i]) | ((unsigned int)f2bf(src[2 * i + 1]) << 16);
    uint4 v; v.x = wd[0]; v.y = wd[1]; v.z = wd[2]; v.w = wd[3];
    wbuf[idx] = v;
}

__device__ __forceinline__ void do_cvt(const float* __restrict__ src,
                                       unsigned short* __restrict__ dst,
                                       int idx, int N, int K, int lds_, int off, int ldd)
{
    if (idx >= N * ldd) return;
    int n = idx / ldd, k = idx - n * ldd;
    float v = (k < K) ? src[(size_t)n * lds_ + off + k] : 0.f;
    dst[idx] = f2bf(v);
}

// segments (blocks of 256): fragU 96 | fragD 96 | rw 520 | uw 768 | dw 768 |
// w0lo 256 | w0hi 256 | w1 128  => 2888
#define PREP_BLOCKS 2888

__global__ __launch_bounds__(256) void prep_all(
    const float* __restrict__ upd_Whh, uint4* __restrict__ wfU,
    const float* __restrict__ dec_Whh, uint4* __restrict__ wfD,
    const float* __restrict__ rr_W, unsigned short* __restrict__ rwbf,
    const float* __restrict__ upd_Wih, unsigned short* __restrict__ uwbf,
    const float* __restrict__ dec_Wih, unsigned short* __restrict__ dwbf,
    const float* __restrict__ er_W0, unsigned short* __restrict__ w0bf,
    const float* __restrict__ er_W1, unsigned short* __restrict__ w1bf)
{
    int bid = blockIdx.x;
    const int tid = threadIdx.x;
    if (bid < 96) { do_packfrag(upd_Whh, wfU, bid * 256 + tid); return; }
    bid -= 96;
    if (bid < 96) { do_packfrag(dec_Whh, wfD, bid * 256 + tid); return; }
    bid -= 96;
    if (bid < 520) { do_cvt(rr_W, rwbf, bid * 256 + tid, 256, 516, 516, 0, 520); return; }
    bid -= 520;
    if (bid < 768) { do_cvt(upd_Wih, uwbf, bid * 256 + tid, 768, 256, 256, 0, 256); return; }
    bid -= 768;
    if (bid < 768) { do_cvt(dec_Wih, dwbf, bid * 256 + tid, 768, 256, 256, 0, 256); return; }
    bid -= 768;
    if (bid < 256) { do_cvt(er_W0, w0bf, bid * 256 + tid, 256, 256, 512, 0, 256); return; }
    bid -= 256;
    if (bid < 256) { do_cvt(er_W0, w0bf + 256 * 256, bid * 256 + tid, 256, 256, 512, 256, 256); return; }
    bid -= 256;
    do_cvt(er_W1, w1bf, bid * 256 + tid, 128, 256, 256, 0, 256);
}

// ---------------------------------------------------------------------------
// K3: bf16 MFMA GEMM, 64x64 tile, K chunked by 128, XOR-swizzled LDS.
// ---------------------------------------------------------------------------
__global__ __launch_bounds__(256) void gemm_mfma(
    const float* __restrict__ A, const unsigned short* __restrict__ B,
    const float* __restrict__ bias, const float* __restrict__ c0,
    float* __restrict__ C, float* __restrict__ C2,
    int M, int N, int K, int lda, int ldb, int mode, int act, int split)
{
    __shared__ __align__(16) unsigned short As[64 * 128];
    __shared__ __align__(16) unsigned short Bs[64 * 128];
    const int tid = threadIdx.x;
    const int m0 = blockIdx.x * 64, n0 = blockIdx.y * 64;
    const int wave = tid >> 6, lane = tid & 63;
    const int lr = lane & 15, quad = lane >> 4;

    v4f acc[4];
    const v4f z4 = {0.f, 0.f, 0.f, 0.f};
#pragma unroll
    for (int nt = 0; nt < 4; ++nt) acc[nt] = z4;

    for (int k0 = 0; k0 < K; k0 += 128) {
        for (int idx = tid; idx < 64 * 32; idx += 256) {
            int r = idx >> 5, kq = idx & 31;
            int k = k0 + kq * 4;
            int m = m0 + r; if (m > M - 1) m = M - 1;
            float4 a = {0.f, 0.f, 0.f, 0.f};
            if (k < K) {
                const float* Ar;
                if (mode == 1) {
                    int ss = m / 127, tt = m - ss * 127;
                    Ar = A + (size_t)(ss * 128 + tt + 1) * lda;
                } else if (mode == 2) {
                    int tt = m % 127;
                    Ar = (tt == 0) ? c0 : (A + (size_t)(m - 1) * lda);
                } else {
                    Ar = A + (size_t)m * lda;
                }
                a = *(const float4*)&Ar[k];
            }
            store4bf(&As[r * 128 + (((kq >> 1) ^ (r & 7)) << 3) + ((kq & 1) << 2)], a);
        }
        for (int idx = tid; idx < 64 * 16; idx += 256) {
            int c = idx >> 4, kb = idx & 15;
            int k = k0 + kb * 8;
            int n = n0 + c;
            uint4 bv = {0u, 0u, 0u, 0u};
            if (k < K) bv = *(const uint4*)&B[(size_t)n * ldb + k];
            *(uint4*)&Bs[c * 128 + ((kb ^ (c & 7)) << 3)] = bv;
        }
        __syncthreads();
        const int row = wave * 16 + lr;
        const int rem = K - k0;
        const int kkm = (rem >= 128) ? 4 : ((rem + 31) >> 5);
        for (int kk = 0; kk < kkm; ++kk) {
            const v8bf af = *(const v8bf*)&As[row * 128 + ((((kk << 2) + quad) ^ (row & 7)) << 3)];
#pragma unroll
            for (int nt = 0; nt < 4; ++nt) {
                const int col = nt * 16 + lr;
                const v8bf bf = *(const v8bf*)&Bs[col * 128 + ((((kk << 2) + quad) ^ (col & 7)) << 3)];
                acc[nt] = __builtin_amdgcn_mfma_f32_16x16x32_bf16(af, bf, acc[nt], 0, 0, 0);
            }
        }
        __syncthreads();
    }
#pragma unroll
    for (int nt = 0; nt < 4; ++nt) {
        const int col = n0 + nt * 16 + lr;
#pragma unroll
        for (int r = 0; r < 4; ++r) {
            const int row = m0 + wave * 16 + quad * 4 + r;
            if (row < M) {
                float v = acc[nt][r];
                if (split) {
                    if (col < 256) C[(size_t)row * 256 + col] = v;
                    else C2[(size_t)row * 256 + (col - 256)] = v + bias[col - 256];
                } else {
                    if (bias) v += bias[col];
                    if (act) v = fmaxf(v, 0.f);
                    C[(size_t)row * N + col] = v;
                }
            }
        }
    }
}

// ---------------------------------------------------------------------------
// K4: GRU scan v6 — MFMA matvec. 512 threads (8 waves) per sample.
// Whh held register-resident as MFMA B-fragments: wave w owns col-tiles
// ct = w*6..w*6+5 (6 x 16 outputs), 8 k-slices -> 48 uint4 frags (192 VGPR).
// A = h broadcast into all 16 rows (8 ds_read_b128/wave/step, 4-addr
// broadcast); D row 0 (lanes 0..15, reg 0) = y. Gates on threads < 256.
// __launch_bounds__(512,2): 256-VGPR cap; total ~240, no spill.
// ---------------------------------------------------------------------------
__global__ __launch_bounds__(512, 2) void gru_scan6(
    const float* __restrict__ gi, const uint4* __restrict__ wf,
    const float* __restrict__ bhh, float* __restrict__ outp, int T)
{
    const int s = blockIdx.x, tid = threadIdx.x;
    const int w = tid >> 6, lane = tid & 63;
    const int quad = lane >> 4;
    __shared__ unsigned int hbuf[2][128];
    __shared__ float dred[768];

    uint4 wfr[6][8];
#pragma unroll
    for (int c = 0; c < 6; ++c)
#pragma unroll
        for (int kk = 0; kk < 8; ++kk)
            wfr[c][kk] = wf[((((w * 6 + c) * 8) + kk) << 6) | lane];

    float br = 0.f, bz = 0.f, bn = 0.f;
    float g_r = 0.f, g_z = 0.f, g_n = 0.f;
    const float* g0 = gi + (size_t)s * T * G_;
    float* o0 = outp + (size_t)s * T * D_;
    float h = 0.f;
    if (tid < 256) {
        br = bhh[tid]; bz = bhh[256 + tid]; bn = bhh[512 + tid];
        g_r = g0[tid]; g_z = g0[256 + tid]; g_n = g0[512 + tid];
    }
    if (tid < 128) { hbuf[0][tid] = 0u; hbuf[1][tid] = 0u; }

    v4f acc[6];
    const v4f z4 = {0.f, 0.f, 0.f, 0.f};
#pragma unroll
    for (int c = 0; c < 6; ++c) acc[c] = z4;
    __syncthreads();

    for (int t = 0; t < T; ++t) {
        float ngr = 0.f, ngz = 0.f, ngn = 0.f;
        if (tid < 256 && t + 1 < T) {
            const float* gn_ = g0 + (size_t)(t + 1) * G_;
            ngr = gn_[tid]; ngz = gn_[256 + tid]; ngn = gn_[512 + tid];
        }
        const unsigned int* hq = hbuf[t & 1];
#pragma unroll
        for (int kk = 0; kk < 8; ++kk) {
            const v8bf af = *(const v8bf*)&hq[kk * 16 + quad * 4];
#pragma unroll
            for (int c = 0; c < 6; ++c)
                acc[c] = __builtin_amdgcn_mfma_f32_16x16x32_bf16(
                    af, u4_to_v8bf(wfr[c][kk]), acc[c], 0, 0, 0);
        }
        // y extraction: D row 0 lives in lanes 0..15, reg 0
        if (lane < 16) {
#pragma unroll
            for (int c = 0; c < 6; ++c)
                dred[(w * 6 + c) * 16 + lane] = acc[c][0];
        }
#pragma unroll
        for (int c = 0; c < 6; ++c) acc[c] = z4;
        __syncthreads();
        if (tid < 256) {
            const float rg = sigmoidf_(g_r + dred[tid] + br);
            const float zg = sigmoidf_(g_z + dred[256 + tid] + bz);
            const float ng = fast_tanh(g_n + rg * (dred[512 + tid] + bn));
            const float hnew = ng + zg * (h - ng);
            h = hnew;
            o0[(size_t)t * D_ + tid] = hnew;
            const float ho = __shfl_xor(hnew, 1);
            if ((tid & 1) == 0)
                hbuf[(t + 1) & 1][tid >> 1] =
                    (unsigned int)f2bf(hnew) | ((unsigned int)f2bf(ho) << 16);
            g_r = ngr; g_z = ngz; g_n = ngn;
        }
        __syncthreads();
    }
}

// ---------------------------------------------------------------------------
// K5: fused edge readout. 64 edges/block. XOR-swizzled h1 tile in LDS.
// ---------------------------------------------------------------------------
__global__ __launch_bounds__(256) void edge_kernel(
    const float* __restrict__ Amat, const float* __restrict__ Bmat,
    const unsigned short* __restrict__ w1bf, const float* __restrict__ b1,
    const float* __restrict__ W2, const float* __restrict__ b2,
    const float* __restrict__ con, float* __restrict__ out)
{
    __shared__ __align__(16) unsigned short h1s[64 * 256];
    __shared__ int ijs[128];
    __shared__ float redw[4][2];
    const int tid = threadIdx.x;
    const int s = blockIdx.y;
    const int e0 = blockIdx.x * 64;

    if (tid < 64) {
        int e = e0 + tid;
        int i = (int)((sqrtf(8.f * (float)e + 1.f) - 1.f) * 0.5f);
        while (((i + 1) * (i + 2)) / 2 <= e) ++i;
        while ((i * (i + 1)) / 2 > e) --i;
        ijs[tid * 2] = i;
        ijs[tid * 2 + 1] = e - (i * (i + 1)) / 2;
    }
    __syncthreads();

    for (int idx = tid; idx < 64 * 64; idx += 256) {
        int e = idx >> 6, k4 = idx & 63;
        int i = ijs[e * 2], j = ijs[e * 2 + 1];
        float4 a = ((const float4*)(Amat + ((size_t)s * NM1 + j) * D_))[k4];
        float4 b = ((const float4*)(Bmat + ((size_t)s * NM1 + i) * D_))[k4];
        float4 hv;
        hv.x = fmaxf(a.x + b.x, 0.f);
        hv.y = fmaxf(a.y + b.y, 0.f);
        hv.z = fmaxf(a.z + b.z, 0.f);
        hv.w = fmaxf(a.w + b.w, 0.f);
        int pc = (k4 >> 1) ^ (e & 7);
        store4bf(&h1s[e * 256 + (pc << 3) + ((k4 & 1) << 2)], hv);
    }
    __syncthreads();

    const int wave = tid >> 6, lane = tid & 63;
    const int lr = lane & 15, quad = lane >> 4;
    const int row = wave * 16 + lr;

    v4f acc[8];
    const v4f vzero = {0.f, 0.f, 0.f, 0.f};
#pragma unroll
    for (int nt = 0; nt < 8; ++nt) acc[nt] = vzero;

#pragma unroll
    for (int kt = 0; kt < 8; ++kt) {
        const int c = kt * 4 + quad;
        const int pc = c ^ (row & 7);
        const v8bf afrag = *reinterpret_cast<const v8bf*>(&h1s[row * 256 + (pc << 3)]);
        const int ko = kt * 32 + quad * 8;
#pragma unroll
        for (int nt = 0; nt < 8; ++nt) {
            const v8bf bfrag = *reinterpret_cast<const v8bf*>(&w1bf[(size_t)(nt * 16 + lr) * D_ + ko]);
            acc[nt] = __builtin_amdgcn_mfma_f32_16x16x32_bf16(afrag, bfrag, acc[nt], 0, 0, 0);
        }
    }

    float w20[8], w21[8], b1v[8];
#pragma unroll
    for (int nt = 0; nt < 8; ++nt) {
        int oc = nt * 16 + lr;
        w20[nt] = W2[oc];
        w21[nt] = W2[128 + oc];
        b1v[nt] = b1[oc];
    }
    const float cb20 = b2[0], cb21 = b2[1];
    float bsum0 = 0.f, bsum1 = 0.f;
#pragma unroll
    for (int r = 0; r < 4; ++r) {
        float l0 = 0.f, l1 = 0.f;
#pragma unroll
        for (int nt = 0; nt < 8; ++nt) {
            float h2 = fmaxf(acc[nt][r] + b1v[nt], 0.f);
            l0 += h2 * w20[nt];
            l1 += h2 * w21[nt];
        }
#pragma unroll
        for (int d = 1; d < 16; d <<= 1) {
            l0 += __shfl_xor(l0, d);
            l1 += __shfl_xor(l1, d);
        }
        if (lr == 0) {
            int e = e0 + wave * 16 + quad * 4 + r;
            l0 += cb20; l1 += cb21;
            float mx = fmaxf(l0, l1);
            float lse = mx + logf(__expf(l0 - mx) + __expf(l1 - mx));
            float lp0 = fmaxf(l0 - lse, -100.f);
            float lp1 = fmaxf(l1 - lse, -100.f);
            float c0v = con[((size_t)s * TRI_ + e) * 2];
            float c1v = con[((size_t)s * TRI_ + e) * 2 + 1];
            bsum0 -= c0v * lp0 + (1.f - c0v) * lp1;
            bsum1 -= c1v * lp1 + (1.f - c1v) * lp0;
        }
    }
#pragma unroll
    for (int d = 1; d < 64; d <<= 1) {
        bsum0 += __shfl_xor(bsum0, d);
        bsum1 += __shfl_xor(bsum1, d);
    }
    if (lane == 0) { redw[wave][0] = bsum0; redw[wave][1] = bsum1; }
    __syncthreads();
    if (tid == 0) {
        float t0 = redw[0][0] + redw[1][0] + redw[2][0] + redw[3][0];
        float t1 = redw[0][1] + redw[1][1] + redw[2][1] + redw[3][1];
        atomicAdd(&out[s * 2], t0);
        atomicAdd(&out[s * 2 + 1], t1);
    }
}

// ---------------------------------------------------------------------------
extern "C" void kernel_launch(void* const* d_in, const int* in_sizes, int n_in,
                              void* d_out, int out_size, void* d_ws, size_t ws_size,
                              hipStream_t stream)
{
    (void)in_sizes; (void)n_in; (void)out_size; (void)ws_size;
    const float* x        = (const float*)d_in[0];
    const float* con      = (const float*)d_in[1];
    const float* z_ph     = (const float*)d_in[2];
    const float* init_ph  = (const float*)d_in[3];
    const float* cc_W0    = (const float*)d_in[4];
    const float* cc_b0    = (const float*)d_in[5];
    const float* cc_W1    = (const float*)d_in[6];
    const float* cc_b1    = (const float*)d_in[7];
    const float* cc_W2    = (const float*)d_in[8];
    const float* cc_b2    = (const float*)d_in[9];
    const float* er_W0    = (const float*)d_in[10];
    const float* er_b0    = (const float*)d_in[11];
    const float* er_W1    = (const float*)d_in[12];
    const float* er_b1    = (const float*)d_in[13];
    const float* er_W2    = (const float*)d_in[14];
    const float* er_b2    = (const float*)d_in[15];
    const float* rr_W     = (const float*)d_in[16];
    const float* rr_b     = (const float*)d_in[17];
    const float* dec_Wih  = (const float*)d_in[18];
    const float* dec_Whh  = (const float*)d_in[19];
    const float* dec_bih  = (const float*)d_in[20];
    const float* dec_bhh  = (const float*)d_in[21];
    const float* upd_Wih  = (const float*)d_in[22];
    const float* upd_Whh  = (const float*)d_in[23];
    const float* upd_bih  = (const float*)d_in[24];
    const float* upd_bhh  = (const float*)d_in[25];
    float* out = (float*)d_out;

    float* ws = (float*)d_ws;
    float* c0v  = ws;                               // 256
    float* gi   = ws + 256;                         // M_*G_
    float* bufA = gi + (size_t)M_ * G_;             // M_*D_ (rnninp, Amat)
    float* bufB = bufA + (size_t)M_ * D_;           // M_*D_ (u_out, Bmat)
    float* memb = bufB + (size_t)M_ * D_;           // M_*D_ (mem)
    unsigned short* w1bf = (unsigned short*)(memb + (size_t)M_ * D_); // 128*256
    unsigned short* rwbf = w1bf + 128 * 256;                          // 256*520
    unsigned short* uwbf = rwbf + 256 * 520;                          // 768*256
    unsigned short* dwbf = uwbf + 768 * 256;                          // 768*256
    unsigned short* w0bf = dwbf + 768 * 256;                          // 512*256
    uint4* wfU = (uint4*)(((size_t)(w0bf + 512 * 256) + 15) & ~(size_t)15); // 24576 uint4
    uint4* wfD = wfU + 48 * 8 * 64;                                   // 24576 uint4

    // 1) c0 + zero out; fused weight prep
    c0_kernel<<<1, 1024, 0, stream>>>(z_ph, init_ph, cc_W0, cc_b0, cc_W1, cc_b1,
                                      cc_W2, cc_b2, c0v, out);
    prep_all<<<PREP_BLOCKS, 256, 0, stream>>>(upd_Whh, wfU, dec_Whh, wfD,
                                              rr_W, rwbf, upd_Wih, uwbf,
                                              dec_Wih, dwbf, er_W0, w0bf,
                                              er_W1, w1bf);
    // 2) rnninp = relu(x[:,1:] @ rr_W.T + rr_b)   -> bufA
    gemm_mfma<<<dim3((M_ + 63) / 64, 256 / 64), 256, 0, stream>>>(
        x, rwbf, rr_b, nullptr, bufA, nullptr, M_, 256, 516, 516, 520, 1, 1, 0);
    // 3) gi_u = rnninp @ upd_Wih.T + upd_bih      -> gi
    gemm_mfma<<<dim3((M_ + 63) / 64, 768 / 64), 256, 0, stream>>>(
        bufA, uwbf, upd_bih, nullptr, gi, nullptr, M_, 768, 256, 256, 256, 0, 0, 0);
    // 4) u_out = GRU(gi_u; upd)                   -> bufB
    gru_scan6<<<S_, 512, 0, stream>>>(gi, wfU, upd_bhh, bufB, NM1);
    // 5) gi_d = content_seq @ dec_Wih.T + dec_bih -> gi
    gemm_mfma<<<dim3((M_ + 63) / 64, 768 / 64), 256, 0, stream>>>(
        bufB, dwbf, dec_bih, c0v, gi, nullptr, M_, 768, 256, 256, 256, 2, 0, 0);
    // 6) mem = GRU(gi_d; dec)                     -> memb
    gru_scan6<<<S_, 512, 0, stream>>>(gi, wfD, dec_bhh, memb, NM1);
    // 7+8) Amat / Bmat = mem @ er_W0 halves (split N=512)
    gemm_mfma<<<dim3((M_ + 63) / 64, 512 / 64), 256, 0, stream>>>(
        memb, w0bf, er_b0, nullptr, bufA, bufB, M_, 512, 256, 256, 256, 0, 0, 1);
    // 9) fused edge readout -> out (atomicAdd)
    edge_kernel<<<dim3(TRI_ / 64, S_), 256, 0, stream>>>(
        bufA, bufB, w1bf, er_b1, er_W2, er_b2, con, out);
}

// Round 7
// 615.659 us; speedup vs baseline: 1.6049x; 1.1092x over previous
//
#include <hip/hip_runtime.h>
#include <cstddef>

#define S_ 32
#define NM1 127
#define D_ 256
#define F_ 516
#define TRI_ 8128
#define G_ 768
#define M_ (S_ * NM1)   // 4064

typedef __bf16 v8bf __attribute__((ext_vector_type(8)));
typedef float v4f __attribute__((ext_vector_type(4)));

__device__ __forceinline__ unsigned short f2bf(float f) {
    unsigned int u = __float_as_uint(f);
    unsigned int r = (u + 0x7FFFu + ((u >> 16) & 1u)) >> 16;
    return (unsigned short)r;
}

__device__ __forceinline__ void store4bf(unsigned short* p, float4 v) {
    ushort4 q;
    q.x = f2bf(v.x); q.y = f2bf(v.y); q.z = f2bf(v.z); q.w = f2bf(v.w);
    *(ushort4*)p = q;
}

__device__ __forceinline__ v8bf u4_to_v8bf(uint4 u) {
    union { uint4 u; v8bf v; } x; x.u = u; return x.v;
}

__device__ __forceinline__ float bflo(unsigned int u) { return __uint_as_float(u << 16); }
__device__ __forceinline__ float bfhi(unsigned int u) { return __uint_as_float(u & 0xffff0000u); }

__device__ __forceinline__ float sigmoidf_(float x) { return 1.f / (1.f + __expf(-x)); }

// branch-free tanh: copysign(1 - 2/(e^{2|x|}+1), x)
__device__ __forceinline__ float fast_tanh(float x) {
    float ax = fabsf(x);
    float e = __expf(2.f * ax);
    float t = 1.f - 2.f / (e + 1.f);
    return copysignf(t, x);
}

// ---------------------------------------------------------------------------
// K1: c0 = MLPReadout([z;init]) through cc_*; also zero d_out. 1 block x 1024.
// ---------------------------------------------------------------------------
__global__ __launch_bounds__(1024) void c0_kernel(
    const float* __restrict__ z_ph, const float* __restrict__ init_ph,
    const float* __restrict__ W0, const float* __restrict__ b0,
    const float* __restrict__ W1, const float* __restrict__ b1,
    const float* __restrict__ W2, const float* __restrict__ b2,
    float* __restrict__ c0_out, float* __restrict__ out_zero)
{
    __shared__ float v[512];
    __shared__ float h0[256];
    __shared__ float h1[128];
    __shared__ float red[4][256];
    __shared__ float red1[8][128];
    const int t = threadIdx.x;
    if (t < 512) v[t] = (t < 256) ? z_ph[t] : init_ph[t - 256];
    if (t < 64) out_zero[t] = 0.f;
    __syncthreads();
    {
        int row = t & 255, part = t >> 8;
        const float* w = W0 + (size_t)row * 512 + part * 128;
        const float* vv = v + part * 128;
        float a = 0.f;
        for (int k = 0; k < 128; ++k) a += w[k] * vv[k];
        red[part][row] = a;
    }
    __syncthreads();
    if (t < 256) {
        float a = b0[t] + red[0][t] + red[1][t] + red[2][t] + red[3][t];
        h0[t] = fmaxf(a, 0.f);
    }
    __syncthreads();
    {
        int row = t & 127, part = t >> 7;
        const float* w = W1 + (size_t)row * 256 + part * 32;
        const float* vv = h0 + part * 32;
        float a = 0.f;
        for (int k = 0; k < 32; ++k) a += w[k] * vv[k];
        red1[part][row] = a;
    }
    __syncthreads();
    if (t < 128) {
        float a = b1[t];
        for (int p = 0; p < 8; ++p) a += red1[p][t];
        h1[t] = fmaxf(a, 0.f);
    }
    __syncthreads();
    {
        int row = t & 255, part = t >> 8;
        const float* w = W2 + (size_t)row * 128 + part * 32;
        const float* vv = h1 + part * 32;
        float a = 0.f;
        for (int k = 0; k < 32; ++k) a += w[k] * vv[k];
        red[part][row] = a;
    }
    __syncthreads();
    if (t < 256) c0_out[t] = b2[t] + red[0][t] + red[1][t] + red[2][t] + red[3][t];
}

// ---------------------------------------------------------------------------
// K2: fused weight prep (one launch, block ranges):
// packfrag: W (ntiles*16 x 256) -> MFMA B-fragment order:
//   wbuf[(ct*8+kk)*64 + lane] = uint4(8 bf16) = W[ct*16+(lane&15)]
//                                               [kk*32+(lane>>4)*8 .. +7]
// cvt: dst[n*ldd+k] = (k<K) ? bf16(src[n*lds+off+k]) : 0
// ---------------------------------------------------------------------------
__device__ __forceinline__ void do_packfrag(const float* __restrict__ W,
                                            uint4* __restrict__ wbuf, int idx,
                                            int ntiles)
{
    if (idx >= ntiles * 8 * 64) return;
    int ct = idx >> 9;
    int rem = idx & 511;
    int kk = rem >> 6;
    int lane = rem & 63;
    int lr = lane & 15, quad = lane >> 4;
    const float* src = W + (size_t)(ct * 16 + lr) * 256 + kk * 32 + quad * 8;
    unsigned int wd[4];
#pragma unroll
    for (int i = 0; i < 4; ++i)
        wd[i] = (unsigned int)f2bf(src[2 * i]) | ((unsigned int)f2bf(src[2 * i + 1]) << 16);
    uint4 v; v.x = wd[0]; v.y = wd[1]; v.z = wd[2]; v.w = wd[3];
    wbuf[idx] = v;
}

__device__ __forceinline__ void do_cvt(const float* __restrict__ src,
                                       unsigned short* __restrict__ dst,
                                       int idx, int N, int K, int lds_, int off, int ldd)
{
    if (idx >= N * ldd) return;
    int n = idx / ldd, k = idx - n * ldd;
    float v = (k < K) ? src[(size_t)n * lds_ + off + k] : 0.f;
    dst[idx] = f2bf(v);
}

// segments (blocks of 256): fragU 96 | fragD 96 | fragW1 16 | rw 520 |
// uw 768 | dw 768 | w0lo 256 | w0hi 256  => 2776
#define PREP_BLOCKS 2776

__global__ __launch_bounds__(256) void prep_all(
    const float* __restrict__ upd_Whh, uint4* __restrict__ wfU,
    const float* __restrict__ dec_Whh, uint4* __restrict__ wfD,
    const float* __restrict__ er_W1, uint4* __restrict__ w1f,
    const float* __restrict__ rr_W, unsigned short* __restrict__ rwbf,
    const float* __restrict__ upd_Wih, unsigned short* __restrict__ uwbf,
    const float* __restrict__ dec_Wih, unsigned short* __restrict__ dwbf,
    const float* __restrict__ er_W0, unsigned short* __restrict__ w0bf)
{
    int bid = blockIdx.x;
    const int tid = threadIdx.x;
    if (bid < 96) { do_packfrag(upd_Whh, wfU, bid * 256 + tid, 48); return; }
    bid -= 96;
    if (bid < 96) { do_packfrag(dec_Whh, wfD, bid * 256 + tid, 48); return; }
    bid -= 96;
    if (bid < 16) { do_packfrag(er_W1, w1f, bid * 256 + tid, 8); return; }
    bid -= 16;
    if (bid < 520) { do_cvt(rr_W, rwbf, bid * 256 + tid, 256, 516, 516, 0, 520); return; }
    bid -= 520;
    if (bid < 768) { do_cvt(upd_Wih, uwbf, bid * 256 + tid, 768, 256, 256, 0, 256); return; }
    bid -= 768;
    if (bid < 768) { do_cvt(dec_Wih, dwbf, bid * 256 + tid, 768, 256, 256, 0, 256); return; }
    bid -= 768;
    if (bid < 256) { do_cvt(er_W0, w0bf, bid * 256 + tid, 256, 256, 512, 0, 256); return; }
    bid -= 256;
    do_cvt(er_W0, w0bf + 256 * 256, bid * 256 + tid, 256, 256, 512, 256, 256);
}

// ---------------------------------------------------------------------------
// K3: bf16 MFMA GEMM, 64x64 tile, K chunked by 128, XOR-swizzled LDS.
// split mode writes bf16 outputs (Amat/Bmat for the edge kernel).
// ---------------------------------------------------------------------------
__global__ __launch_bounds__(256) void gemm_mfma(
    const float* __restrict__ A, const unsigned short* __restrict__ B,
    const float* __restrict__ bias, const float* __restrict__ c0,
    float* __restrict__ C, float* __restrict__ C2,
    int M, int N, int K, int lda, int ldb, int mode, int act, int split)
{
    __shared__ __align__(16) unsigned short As[64 * 128];
    __shared__ __align__(16) unsigned short Bs[64 * 128];
    const int tid = threadIdx.x;
    const int m0 = blockIdx.x * 64, n0 = blockIdx.y * 64;
    const int wave = tid >> 6, lane = tid & 63;
    const int lr = lane & 15, quad = lane >> 4;

    v4f acc[4];
    const v4f z4 = {0.f, 0.f, 0.f, 0.f};
#pragma unroll
    for (int nt = 0; nt < 4; ++nt) acc[nt] = z4;

    for (int k0 = 0; k0 < K; k0 += 128) {
        for (int idx = tid; idx < 64 * 32; idx += 256) {
            int r = idx >> 5, kq = idx & 31;
            int k = k0 + kq * 4;
            int m = m0 + r; if (m > M - 1) m = M - 1;
            float4 a = {0.f, 0.f, 0.f, 0.f};
            if (k < K) {
                const float* Ar;
                if (mode == 1) {
                    int ss = m / 127, tt = m - ss * 127;
                    Ar = A + (size_t)(ss * 128 + tt + 1) * lda;
                } else if (mode == 2) {
                    int tt = m % 127;
                    Ar = (tt == 0) ? c0 : (A + (size_t)(m - 1) * lda);
                } else {
                    Ar = A + (size_t)m * lda;
                }
                a = *(const float4*)&Ar[k];
            }
            store4bf(&As[r * 128 + (((kq >> 1) ^ (r & 7)) << 3) + ((kq & 1) << 2)], a);
        }
        for (int idx = tid; idx < 64 * 16; idx += 256) {
            int c = idx >> 4, kb = idx & 15;
            int k = k0 + kb * 8;
            int n = n0 + c;
            uint4 bv = {0u, 0u, 0u, 0u};
            if (k < K) bv = *(const uint4*)&B[(size_t)n * ldb + k];
            *(uint4*)&Bs[c * 128 + ((kb ^ (c & 7)) << 3)] = bv;
        }
        __syncthreads();
        const int row = wave * 16 + lr;
        const int rem = K - k0;
        const int kkm = (rem >= 128) ? 4 : ((rem + 31) >> 5);
        for (int kk = 0; kk < kkm; ++kk) {
            const v8bf af = *(const v8bf*)&As[row * 128 + ((((kk << 2) + quad) ^ (row & 7)) << 3)];
#pragma unroll
            for (int nt = 0; nt < 4; ++nt) {
                const int col = nt * 16 + lr;
                const v8bf bf = *(const v8bf*)&Bs[col * 128 + ((((kk << 2) + quad) ^ (col & 7)) << 3)];
                acc[nt] = __builtin_amdgcn_mfma_f32_16x16x32_bf16(af, bf, acc[nt], 0, 0, 0);
            }
        }
        __syncthreads();
    }
#pragma unroll
    for (int nt = 0; nt < 4; ++nt) {
        const int col = n0 + nt * 16 + lr;
#pragma unroll
        for (int r = 0; r < 4; ++r) {
            const int row = m0 + wave * 16 + quad * 4 + r;
            if (row < M) {
                float v = acc[nt][r];
                if (split) {
                    // bf16 outputs for edge kernel
                    if (col < 256)
                        ((unsigned short*)C)[(size_t)row * 256 + col] = f2bf(v);
                    else
                        ((unsigned short*)C2)[(size_t)row * 256 + (col - 256)] =
                            f2bf(v + bias[col - 256]);
                } else {
                    if (bias) v += bias[col];
                    if (act) v = fmaxf(v, 0.f);
                    C[(size_t)row * N + col] = v;
                }
            }
        }
    }
}

// ---------------------------------------------------------------------------
// K4: GRU scan v6 — MFMA matvec (unchanged from R6).
// ---------------------------------------------------------------------------
__global__ __launch_bounds__(512, 2) void gru_scan6(
    const float* __restrict__ gi, const uint4* __restrict__ wf,
    const float* __restrict__ bhh, float* __restrict__ outp, int T)
{
    const int s = blockIdx.x, tid = threadIdx.x;
    const int w = tid >> 6, lane = tid & 63;
    const int quad = lane >> 4;
    __shared__ unsigned int hbuf[2][128];
    __shared__ float dred[768];

    uint4 wfr[6][8];
#pragma unroll
    for (int c = 0; c < 6; ++c)
#pragma unroll
        for (int kk = 0; kk < 8; ++kk)
            wfr[c][kk] = wf[((((w * 6 + c) * 8) + kk) << 6) | lane];

    float br = 0.f, bz = 0.f, bn = 0.f;
    float g_r = 0.f, g_z = 0.f, g_n = 0.f;
    const float* g0 = gi + (size_t)s * T * G_;
    float* o0 = outp + (size_t)s * T * D_;
    float h = 0.f;
    if (tid < 256) {
        br = bhh[tid]; bz = bhh[256 + tid]; bn = bhh[512 + tid];
        g_r = g0[tid]; g_z = g0[256 + tid]; g_n = g0[512 + tid];
    }
    if (tid < 128) { hbuf[0][tid] = 0u; hbuf[1][tid] = 0u; }

    v4f acc[6];
    const v4f z4 = {0.f, 0.f, 0.f, 0.f};
#pragma unroll
    for (int c = 0; c < 6; ++c) acc[c] = z4;
    __syncthreads();

    for (int t = 0; t < T; ++t) {
        float ngr = 0.f, ngz = 0.f, ngn = 0.f;
        if (tid < 256 && t + 1 < T) {
            const float* gn_ = g0 + (size_t)(t + 1) * G_;
            ngr = gn_[tid]; ngz = gn_[256 + tid]; ngn = gn_[512 + tid];
        }
        const unsigned int* hq = hbuf[t & 1];
#pragma unroll
        for (int kk = 0; kk < 8; ++kk) {
            const v8bf af = *(const v8bf*)&hq[kk * 16 + quad * 4];
#pragma unroll
            for (int c = 0; c < 6; ++c)
                acc[c] = __builtin_amdgcn_mfma_f32_16x16x32_bf16(
                    af, u4_to_v8bf(wfr[c][kk]), acc[c], 0, 0, 0);
        }
        if (lane < 16) {
#pragma unroll
            for (int c = 0; c < 6; ++c)
                dred[(w * 6 + c) * 16 + lane] = acc[c][0];
        }
#pragma unroll
        for (int c = 0; c < 6; ++c) acc[c] = z4;
        __syncthreads();
        if (tid < 256) {
            const float rg = sigmoidf_(g_r + dred[tid] + br);
            const float zg = sigmoidf_(g_z + dred[256 + tid] + bz);
            const float ng = fast_tanh(g_n + rg * (dred[512 + tid] + bn));
            const float hnew = ng + zg * (h - ng);
            h = hnew;
            o0[(size_t)t * D_ + tid] = hnew;
            const float ho = __shfl_xor(hnew, 1);
            if ((tid & 1) == 0)
                hbuf[(t + 1) & 1][tid >> 1] =
                    (unsigned int)f2bf(hnew) | ((unsigned int)f2bf(ho) << 16);
            g_r = ngr; g_z = ngz; g_n = ngn;
        }
        __syncthreads();
    }
}

// ---------------------------------------------------------------------------
// K5: edge readout v2. 64 edges/block. W1 register-resident as B-frags
// (wave w owns col-tiles 2w, 2w+1). bf16 Amat/Bmat staging (half traffic).
// uint4 XOR swizzle: conflict-free stores and A-frag reads (16-lane phases).
// ---------------------------------------------------------------------------
__global__ __launch_bounds__(256, 3) void edge_kernel2(
    const unsigned short* __restrict__ Abf, const unsigned short* __restrict__ Bbf,
    const uint4* __restrict__ w1f, const float* __restrict__ b1,
    const float* __restrict__ W2, const float* __restrict__ b2,
    const float* __restrict__ con, float* __restrict__ out)
{
    __shared__ __align__(16) unsigned short h1s[64 * 256];
    __shared__ int ijs[128];
    __shared__ float part[4][64][2];
    const int tid = threadIdx.x;
    const int s = blockIdx.y;
    const int e0 = blockIdx.x * 64;
    const int wave = tid >> 6, lane = tid & 63;
    const int lr = lane & 15, quad = lane >> 4;

    // W1 B-fragments for this wave's two col-tiles (loaded once)
    uint4 wfr[2][8];
#pragma unroll
    for (int c = 0; c < 2; ++c)
#pragma unroll
        for (int kk = 0; kk < 8; ++kk)
            wfr[c][kk] = w1f[((((wave * 2 + c) * 8) + kk) << 6) | lane];

    // per-lane epilogue constants (cols wave*32+lr and wave*32+16+lr)
    const int ca = wave * 32 + lr, cb = wave * 32 + 16 + lr;
    const float b1a = b1[ca], b1b = b1[cb];
    const float w20a = W2[ca], w20b = W2[cb];
    const float w21a = W2[128 + ca], w21b = W2[128 + cb];
    const float cb20 = b2[0], cb21 = b2[1];

    if (tid < 64) {
        int e = e0 + tid;
        int i = (int)((sqrtf(8.f * (float)e + 1.f) - 1.f) * 0.5f);
        while (((i + 1) * (i + 2)) / 2 <= e) ++i;
        while ((i * (i + 1)) / 2 > e) --i;
        ijs[tid * 2] = i;
        ijs[tid * 2 + 1] = e - (i * (i + 1)) / 2;
    }
    __syncthreads();

    // stage h1 = relu(A_j + B_i) in bf16, uint4 granularity, swizzled
    {
        const unsigned short* Aro = Abf + (size_t)s * NM1 * 256;
        const unsigned short* Bro = Bbf + (size_t)s * NM1 * 256;
#pragma unroll
        for (int it = 0; it < 8; ++it) {
            int idx = tid + it * 256;
            int e = idx >> 5, k8 = idx & 31;
            int i = ijs[2 * e], j = ijs[2 * e + 1];
            uint4 av = *(const uint4*)&Aro[(size_t)j * 256 + k8 * 8];
            uint4 bv = *(const uint4*)&Bro[(size_t)i * 256 + k8 * 8];
            unsigned int rr[4];
#pragma unroll
            for (int wd = 0; wd < 4; ++wd) {
                unsigned int aw = (&av.x)[wd], bw = (&bv.x)[wd];
                float lo = fmaxf(bflo(aw) + bflo(bw), 0.f);
                float hi = fmaxf(bfhi(aw) + bfhi(bw), 0.f);
                rr[wd] = (unsigned int)f2bf(lo) | ((unsigned int)f2bf(hi) << 16);
            }
            uint4 hv; hv.x = rr[0]; hv.y = rr[1]; hv.z = rr[2]; hv.w = rr[3];
            *(uint4*)&h1s[e * 256 + ((k8 ^ (e & 7)) << 3)] = hv;
        }
    }
    __syncthreads();

    // MFMA: 4 row-tiles x 2 col-tiles x 8 k-slices
    v4f acc[4][2];
    const v4f z4 = {0.f, 0.f, 0.f, 0.f};
#pragma unroll
    for (int rt = 0; rt < 4; ++rt) { acc[rt][0] = z4; acc[rt][1] = z4; }

#pragma unroll
    for (int kk = 0; kk < 8; ++kk) {
        v8bf af[4];
#pragma unroll
        for (int rt = 0; rt < 4; ++rt) {
            const int row = rt * 16 + lr;
            af[rt] = *(const v8bf*)&h1s[row * 256 + ((((kk << 2) + quad) ^ (row & 7)) << 3)];
        }
#pragma unroll
        for (int rt = 0; rt < 4; ++rt) {
            acc[rt][0] = __builtin_amdgcn_mfma_f32_16x16x32_bf16(
                af[rt], u4_to_v8bf(wfr[0][kk]), acc[rt][0], 0, 0, 0);
            acc[rt][1] = __builtin_amdgcn_mfma_f32_16x16x32_bf16(
                af[rt], u4_to_v8bf(wfr[1][kk]), acc[rt][1], 0, 0, 0);
        }
    }

    // per-wave partial logits over its 32 cols
#pragma unroll
    for (int rt = 0; rt < 4; ++rt) {
#pragma unroll
        for (int r = 0; r < 4; ++r) {
            float h2a = fmaxf(acc[rt][0][r] + b1a, 0.f);
            float h2b = fmaxf(acc[rt][1][r] + b1b, 0.f);
            float p0 = h2a * w20a + h2b * w20b;
            float p1 = h2a * w21a + h2b * w21b;
#pragma unroll
            for (int d = 1; d < 16; d <<= 1) {
                p0 += __shfl_xor(p0, d);
                p1 += __shfl_xor(p1, d);
            }
            if (lr == 0) {
                int e = rt * 16 + quad * 4 + r;
                part[wave][e][0] = p0;
                part[wave][e][1] = p1;
            }
        }
    }
    __syncthreads();

    if (tid < 64) {
        float l0 = part[0][tid][0] + part[1][tid][0] + part[2][tid][0] + part[3][tid][0] + cb20;
        float l1 = part[0][tid][1] + part[1][tid][1] + part[2][tid][1] + part[3][tid][1] + cb21;
        int e = e0 + tid;
        float mx = fmaxf(l0, l1);
        float lse = mx + logf(__expf(l0 - mx) + __expf(l1 - mx));
        float lp0 = fmaxf(l0 - lse, -100.f);
        float lp1 = fmaxf(l1 - lse, -100.f);
        float c0v = con[((size_t)s * TRI_ + e) * 2];
        float c1v = con[((size_t)s * TRI_ + e) * 2 + 1];
        float bsum0 = -(c0v * lp0 + (1.f - c0v) * lp1);
        float bsum1 = -(c1v * lp1 + (1.f - c1v) * lp0);
#pragma unroll
        for (int d = 1; d < 64; d <<= 1) {
            bsum0 += __shfl_xor(bsum0, d);
            bsum1 += __shfl_xor(bsum1, d);
        }
        if (tid == 0) {
            atomicAdd(&out[s * 2], bsum0);
            atomicAdd(&out[s * 2 + 1], bsum1);
        }
    }
}

// ---------------------------------------------------------------------------
extern "C" void kernel_launch(void* const* d_in, const int* in_sizes, int n_in,
                              void* d_out, int out_size, void* d_ws, size_t ws_size,
                              hipStream_t stream)
{
    (void)in_sizes; (void)n_in; (void)out_size; (void)ws_size;
    const float* x        = (const float*)d_in[0];
    const float* con      = (const float*)d_in[1];
    const float* z_ph     = (const float*)d_in[2];
    const float* init_ph  = (const float*)d_in[3];
    const float* cc_W0    = (const float*)d_in[4];
    const float* cc_b0    = (const float*)d_in[5];
    const float* cc_W1    = (const float*)d_in[6];
    const float* cc_b1    = (const float*)d_in[7];
    const float* cc_W2    = (const float*)d_in[8];
    const float* cc_b2    = (const float*)d_in[9];
    const float* er_W0    = (const float*)d_in[10];
    const float* er_b0    = (const float*)d_in[11];
    const float* er_W1    = (const float*)d_in[12];
    const float* er_b1    = (const float*)d_in[13];
    const float* er_W2    = (const float*)d_in[14];
    const float* er_b2    = (const float*)d_in[15];
    const float* rr_W     = (const float*)d_in[16];
    const float* rr_b     = (const float*)d_in[17];
    const float* dec_Wih  = (const float*)d_in[18];
    const float* dec_Whh  = (const float*)d_in[19];
    const float* dec_bih  = (const float*)d_in[20];
    const float* dec_bhh  = (const float*)d_in[21];
    const float* upd_Wih  = (const float*)d_in[22];
    const float* upd_Whh  = (const float*)d_in[23];
    const float* upd_bih  = (const float*)d_in[24];
    const float* upd_bhh  = (const float*)d_in[25];
    float* out = (float*)d_out;

    float* ws = (float*)d_ws;
    float* c0v  = ws;                               // 256
    float* gi   = ws + 256;                         // M_*G_
    float* bufA = gi + (size_t)M_ * G_;             // M_*D_ (rnninp fp32, Amat bf16)
    float* bufB = bufA + (size_t)M_ * D_;           // M_*D_ (u_out fp32, Bmat bf16)
    float* memb = bufB + (size_t)M_ * D_;           // M_*D_ (mem fp32)
    unsigned short* rwbf = (unsigned short*)(memb + (size_t)M_ * D_); // 256*520
    unsigned short* uwbf = rwbf + 256 * 520;                          // 768*256
    unsigned short* dwbf = uwbf + 768 * 256;                          // 768*256
    unsigned short* w0bf = dwbf + 768 * 256;                          // 512*256
    uint4* wfU = (uint4*)(((size_t)(w0bf + 512 * 256) + 15) & ~(size_t)15); // 24576
    uint4* wfD = wfU + 48 * 8 * 64;                                   // 24576
    uint4* w1f = wfD + 48 * 8 * 64;                                   // 4096

    // 1) c0 + zero out; fused weight prep
    c0_kernel<<<1, 1024, 0, stream>>>(z_ph, init_ph, cc_W0, cc_b0, cc_W1, cc_b1,
                                      cc_W2, cc_b2, c0v, out);
    prep_all<<<PREP_BLOCKS, 256, 0, stream>>>(upd_Whh, wfU, dec_Whh, wfD,
                                              er_W1, w1f,
                                              rr_W, rwbf, upd_Wih, uwbf,
                                              dec_Wih, dwbf, er_W0, w0bf);
    // 2) rnninp = relu(x[:,1:] @ rr_W.T + rr_b)   -> bufA
    gemm_mfma<<<dim3((M_ + 63) / 64, 256 / 64), 256, 0, stream>>>(
        x, rwbf, rr_b, nullptr, bufA, nullptr, M_, 256, 516, 516, 520, 1, 1, 0);
    // 3) gi_u = rnninp @ upd_Wih.T + upd_bih      -> gi
    gemm_mfma<<<dim3((M_ + 63) / 64, 768 / 64), 256, 0, stream>>>(
        bufA, uwbf, upd_bih, nullptr, gi, nullptr, M_, 768, 256, 256, 256, 0, 0, 0);
    // 4) u_out = GRU(gi_u; upd)                   -> bufB
    gru_scan6<<<S_, 512, 0, stream>>>(gi, wfU, upd_bhh, bufB, NM1);
    // 5) gi_d = content_seq @ dec_Wih.T + dec_bih -> gi
    gemm_mfma<<<dim3((M_ + 63) / 64, 768 / 64), 256, 0, stream>>>(
        bufB, dwbf, dec_bih, c0v, gi, nullptr, M_, 768, 256, 256, 256, 2, 0, 0);
    // 6) mem = GRU(gi_d; dec)                     -> memb
    gru_scan6<<<S_, 512, 0, stream>>>(gi, wfD, dec_bhh, memb, NM1);
    // 7+8) Amat / Bmat = mem @ er_W0 halves (split N=512, bf16 out)
    gemm_mfma<<<dim3((M_ + 63) / 64, 512 / 64), 256, 0, stream>>>(
        memb, w0bf, er_b0, nullptr, bufA, bufB, M_, 512, 256, 256, 256, 0, 0, 1);
    // 9) fused edge readout -> out (atomicAdd)
    edge_kernel2<<<dim3(TRI_ / 64, S_), 256, 0, stream>>>(
        (const unsigned short*)bufA, (const unsigned short*)bufB,
        w1f, er_b1, er_W2, er_b2, con, out);
}